// Round 6
// baseline (4106.414 us; speedup 1.0000x reference)
//
#include <hip/hip_runtime.h>
#include <cstdint>
#include <cstddef>

// ---- problem constants (from reference) ----
#define N_    16
#define C_    16
#define T_    300
#define V_    25
#define D_    400
#define H_    2
#define DH_   200
#define FF_   1600
#define L_    9
#define W_    291          // T - L
#define NW_   (N_*W_)      // 4656 windows
#define ROWS_ (NW_*L_)     // 41904 encoder rows
#define NT_   (N_*T_)      // 4800 tokens
#define CW_   256          // windows per chunk (2304 rows)

// ---- workspace layout (bytes), total 35,942,400 ----
#define XS_OFF   0u          // xs  bf16 : 3,840,000
#define QKV_OFF  3840000u    // qkv bf16 : 11,520,000
#define ACC_OFF  15360000u   // acc fp32 : 7,680,000
#define OC_OFF   23040000u   // o_c bf16 : 1,843,200
#define YC_OFF   24883200u   // y_c bf16 : 1,843,200
#define HC_OFF   26726400u   // h_c bf16 : 1,843,200
#define FFC_OFF  28569600u   // ffc bf16 : 7,372,800

using u16 = unsigned short;
using u32 = unsigned int;

__device__ __forceinline__ float bf2f(u16 u){
  return __uint_as_float(((u32)u) << 16);
}
__device__ __forceinline__ u16 f2bf(float f){
  u32 i = __float_as_uint(f);
  u32 r = (i + 0x7fffu + ((i >> 16) & 1u)) >> 16;   // RNE
  return (u16)r;
}
__device__ __forceinline__ void load4bf(const u16* p, float* o){
  uint2 r = *reinterpret_cast<const uint2*>(p);
  o[0] = bf2f((u16)(r.x & 0xffffu));
  o[1] = bf2f((u16)(r.x >> 16));
  o[2] = bf2f((u16)(r.y & 0xffffu));
  o[3] = bf2f((u16)(r.y >> 16));
}
__device__ __forceinline__ void load4f(const float* p, float* o){
  float4 r = *reinterpret_cast<const float4*>(p);
  o[0] = r.x; o[1] = r.y; o[2] = r.z; o[3] = r.w;
}

__global__ __launch_bounds__(256) void zero_kernel(float* __restrict__ acc, int n){
  int idx = blockIdx.x * 256 + threadIdx.x;
  if (idx < n) acc[idx] = 0.f;
}

// ---- xs[n,t,d] = x[n, d&15, t, d>>4] + pe[t,d] ; fp32 in -> bf16 out ----
__global__ __launch_bounds__(256) void embed_kernel(const float* __restrict__ x,
                                                    const float* __restrict__ pe,
                                                    u16* __restrict__ xs){
  int idx = blockIdx.x * 256 + threadIdx.x;
  if (idx >= NT_ * D_) return;
  int d  = idx % D_;
  int nt = idx / D_;
  int t  = nt % T_;
  int n  = nt / T_;
  int c  = d & 15;
  int v  = d >> 4;
  float val = x[(((size_t)(n*C_ + c))*T_ + t)*V_ + v] + pe[t*D_ + d];
  xs[idx] = f2bf(val);
}

// ---- GEMM: C[m,n] = act(sum_k A[m,k]*B[n,k] + bias[n]) ----
// A bf16 [M,K], B fp32 [N,K] (weights), bias fp32, C bf16. fp32 accumulate.
template<int ACT>
__global__ __launch_bounds__(256) void gemm_bt(const u16* __restrict__ A,
                                               const float* __restrict__ B,
                                               const float* __restrict__ bias,
                                               u16* __restrict__ C,
                                               int M, int N, int K){
  __shared__ float As[16][68];
  __shared__ float Bs[16][68];
  const int tid = threadIdx.x;
  const int tx = tid & 15, ty = tid >> 4;
  const int m0 = blockIdx.y * 64, n0 = blockIdx.x * 64;
  const int lm = tid >> 2;          // 0..63
  const int lk = (tid & 3) << 2;    // 0,4,8,12

  float acc[4][4];
  #pragma unroll
  for (int i = 0; i < 4; ++i)
    #pragma unroll
    for (int j = 0; j < 4; ++j) acc[i][j] = 0.f;

  const int gm = m0 + lm;
  const int gn = n0 + lm;

  for (int kt = 0; kt < K; kt += 16){
    float av[4], bv[4];
    if (gm < M) load4bf(A + (size_t)gm * K + kt + lk, av);
    else { av[0]=av[1]=av[2]=av[3]=0.f; }
    if (gn < N) load4f(B + (size_t)gn * K + kt + lk, bv);
    else { bv[0]=bv[1]=bv[2]=bv[3]=0.f; }
    #pragma unroll
    for (int i = 0; i < 4; ++i){ As[lk+i][lm] = av[i]; Bs[lk+i][lm] = bv[i]; }
    __syncthreads();
    #pragma unroll
    for (int kk = 0; kk < 16; ++kk){
      const float4 a4 = *reinterpret_cast<const float4*>(&As[kk][ty << 2]);
      const float4 b4 = *reinterpret_cast<const float4*>(&Bs[kk][tx << 2]);
      float ar[4] = {a4.x, a4.y, a4.z, a4.w};
      float br[4] = {b4.x, b4.y, b4.z, b4.w};
      #pragma unroll
      for (int i = 0; i < 4; ++i)
        #pragma unroll
        for (int j = 0; j < 4; ++j)
          acc[i][j] += ar[i] * br[j];
    }
    __syncthreads();
  }

  float bj[4];
  #pragma unroll
  for (int j = 0; j < 4; ++j){
    int n = n0 + (tx << 2) + j;
    bj[j] = (n < N) ? bias[n] : 0.f;
  }
  #pragma unroll
  for (int i = 0; i < 4; ++i){
    int m = m0 + (ty << 2) + i;
    if (m >= M) continue;
    #pragma unroll
    for (int j = 0; j < 4; ++j){
      int n = n0 + (tx << 2) + j;
      if (n >= N) continue;
      float v = acc[i][j] + bj[j];
      if (ACT) v = 0.5f * v * (1.f + erff(v * 0.70710678f));   // exact gelu
      C[(size_t)m * N + n] = f2bf(v);
    }
  }
}

// ---- attention for one chunk of windows ----
__global__ __launch_bounds__(256) void attn_kernel(const u16* __restrict__ qkv,
                                                   u16* __restrict__ o,
                                                   int g0){
  __shared__ float sq[L_ * 1200];
  __shared__ float sc[H_ * L_ * L_];
  __shared__ float att[H_ * L_ * L_];
  const int g = g0 + blockIdx.x;
  const int n = g / W_, w = g % W_;
  const int tid = threadIdx.x;

  for (int i = tid; i < L_ * 1200; i += 256){
    int l = i / 1200, j = i % 1200;
    sq[i] = bf2f(qkv[((size_t)(n*T_ + w + l)) * 1200 + j]);
  }
  __syncthreads();

  if (tid < H_ * L_ * L_){
    int h = tid / (L_*L_), rem = tid % (L_*L_), qi = rem / L_, ki = rem % L_;
    const float* qp = &sq[qi*1200 + h*DH_];
    const float* kp = &sq[ki*1200 + D_ + h*DH_];
    float s = 0.f;
    for (int dd = 0; dd < DH_; ++dd) s += qp[dd] * kp[dd];
    sc[tid] = s * 0.07071067811865475f;  // 1/sqrt(200)
  }
  __syncthreads();

  if (tid < H_ * L_){
    int base = tid * L_;
    float mx = -1e30f;
    for (int j = 0; j < L_; ++j) mx = fmaxf(mx, sc[base + j]);
    float sum = 0.f;
    for (int j = 0; j < L_; ++j){ float e = __expf(sc[base + j] - mx); att[base + j] = e; sum += e; }
    float inv = 1.f / sum;
    for (int j = 0; j < L_; ++j) att[base + j] *= inv;
  }
  __syncthreads();

  for (int i = tid; i < L_ * D_; i += 256){
    int l = i / D_, d = i % D_;
    int h = d / DH_;
    float acc = 0.f;
    #pragma unroll
    for (int ki = 0; ki < L_; ++ki)
      acc += att[h*(L_*L_) + l*L_ + ki] * sq[ki*1200 + 2*D_ + d];
    o[((size_t)blockIdx.x * L_ + l) * D_ + d] = f2bf(acc);
  }
}

// ---- LN(a_row + b_row) over chunk rows; gather=1: a from xs window ----
//      a and out may alias (row-local, reads complete before writes).
__global__ __launch_bounds__(256) void resln_kernel(const u16* a,
                                                    const u16* b,
                                                    const float* __restrict__ gam,
                                                    const float* __restrict__ bet,
                                                    u16* out,
                                                    const u16* __restrict__ xs,
                                                    int g0, int gather){
  const int r = blockIdx.x;
  const int tid = threadIdx.x;
  const u16* arow;
  if (gather){
    int g = g0 + r / L_;
    int l = r % L_;
    int n = g / W_, w = g % W_;
    arow = xs + ((size_t)(n*T_ + w + l)) * D_;
  } else {
    arow = a + (size_t)r * D_;
  }
  const u16* brow = b + (size_t)r * D_;

  float v0 = bf2f(arow[tid]) + bf2f(brow[tid]);
  const bool has1 = (tid + 256) < D_;
  float v1 = has1 ? (bf2f(arow[tid + 256]) + bf2f(brow[tid + 256])) : 0.f;

  __shared__ float red[256];
  red[tid] = v0 + v1;
  __syncthreads();
  for (int s = 128; s > 0; s >>= 1){
    if (tid < s) red[tid] += red[tid + s];
    __syncthreads();
  }
  float mean = red[0] * (1.f / D_);
  __syncthreads();
  float d0 = v0 - mean;
  float d1 = has1 ? (v1 - mean) : 0.f;
  red[tid] = d0*d0 + d1*d1;
  __syncthreads();
  for (int s = 128; s > 0; s >>= 1){
    if (tid < s) red[tid] += red[tid + s];
    __syncthreads();
  }
  float rstd = rsqrtf(red[0] * (1.f / D_) + 1e-5f);
  out[(size_t)r * D_ + tid] = f2bf(d0 * rstd * gam[tid] + bet[tid]);
  if (has1)
    out[(size_t)r * D_ + tid + 256] = f2bf(d1 * rstd * gam[tid + 256] + bet[tid + 256]);
}

// ---- scatter-add chunk rows into fp32 accumulator [N,T,D] ----
__global__ __launch_bounds__(256) void scatter_add_kernel(const u16* __restrict__ win,
                                                          float* __restrict__ acc,
                                                          int g0, int nrows){
  int idx = blockIdx.x * 256 + threadIdx.x;
  if (idx >= nrows * D_) return;
  int d = idx % D_;
  int r = idx / D_;
  int g = g0 + r / L_;
  int l = r % L_;
  int n = g / W_, w = g % W_;
  int t = (w >> 1) + l;
  atomicAdd(acc + ((size_t)(n*T_ + t)) * D_ + d, bf2f(win[idx]));
}

// ---- acc[n,t,d] -> out[n,c,t,v] FP32 (reference output dtype) ----
__global__ __launch_bounds__(256) void final_kernel(const float* __restrict__ acc,
                                                    float* __restrict__ dout){
  int idx = blockIdx.x * 256 + threadIdx.x;
  if (idx >= NT_ * D_) return;
  int d  = idx % D_;
  int nt = idx / D_;
  int t  = nt % T_;
  int n  = nt / T_;
  dout[(((size_t)(n*C_ + (d & 15)))*T_ + t)*V_ + (d >> 4)] = acc[idx];
}

extern "C" void kernel_launch(void* const* d_in, const int* in_sizes, int n_in,
                              void* d_out, int out_size, void* d_ws, size_t ws_size,
                              hipStream_t stream){
  (void)in_sizes; (void)n_in; (void)out_size; (void)ws_size;
  const float* x     = (const float*)d_in[0];
  const float* pe    = (const float*)d_in[1];
  const float* w_in  = (const float*)d_in[2];
  const float* b_in  = (const float*)d_in[3];
  const float* w_out = (const float*)d_in[4];
  const float* b_out = (const float*)d_in[5];
  const float* w1    = (const float*)d_in[6];
  const float* b1    = (const float*)d_in[7];
  const float* w2    = (const float*)d_in[8];
  const float* b2    = (const float*)d_in[9];
  const float* ln1g  = (const float*)d_in[10];
  const float* ln1b  = (const float*)d_in[11];
  const float* ln2g  = (const float*)d_in[12];
  const float* ln2b  = (const float*)d_in[13];

  char* ws = (char*)d_ws;
  u16*   xs  = (u16*)(ws + XS_OFF);
  u16*   qkv = (u16*)(ws + QKV_OFF);
  float* acc = (float*)(ws + ACC_OFF);
  u16*   o_c = (u16*)(ws + OC_OFF);
  u16*   y_c = (u16*)(ws + YC_OFF);
  u16*   h_c = (u16*)(ws + HC_OFF);
  u16*   ffc = (u16*)(ws + FFC_OFF);

  zero_kernel<<<(NT_*D_ + 255)/256, 256, 0, stream>>>(acc, NT_*D_);
  embed_kernel<<<(NT_*D_ + 255)/256, 256, 0, stream>>>(x, pe, xs);

  gemm_bt<0><<<dim3((1200+63)/64, (NT_+63)/64), 256, 0, stream>>>(
      xs, w_in, b_in, qkv, NT_, 1200, D_);

  for (int g0 = 0; g0 < NW_; g0 += CW_){
    int cw = NW_ - g0; if (cw > CW_) cw = CW_;
    int m = cw * L_;
    int gy = (m + 63) / 64;

    attn_kernel<<<cw, 256, 0, stream>>>(qkv, o_c, g0);

    gemm_bt<0><<<dim3((D_+63)/64, gy), 256, 0, stream>>>(
        o_c, w_out, b_out, y_c, m, D_, D_);

    resln_kernel<<<m, 256, 0, stream>>>(nullptr, y_c, ln1g, ln1b, h_c, xs, g0, 1);

    gemm_bt<1><<<dim3(FF_/64, gy), 256, 0, stream>>>(
        h_c, w1, b1, ffc, m, FF_, D_);

    gemm_bt<0><<<dim3((D_+63)/64, gy), 256, 0, stream>>>(
        ffc, w2, b2, y_c, m, D_, FF_);

    resln_kernel<<<m, 256, 0, stream>>>(h_c, y_c, ln2g, ln2b, h_c, nullptr, g0, 0);

    scatter_add_kernel<<<(m*D_ + 255)/256, 256, 0, stream>>>(h_c, acc, g0, m);
  }

  final_kernel<<<(NT_*D_ + 255)/256, 256, 0, stream>>>(acc, (float*)d_out);
}

// Round 7
// 966.819 us; speedup vs baseline: 4.2473x; 4.2473x over previous
//
#include <hip/hip_runtime.h>
#include <cstdint>
#include <cstddef>

// ---- problem constants ----
#define N_    16
#define C_    16
#define T_    300
#define V_    25
#define D_    400
#define H_    2
#define DH_   200
#define FF_   1600
#define L_    9
#define W_    291
#define NW_   (N_*W_)      // 4656
#define ROWS_ (NW_*L_)     // 41904
#define NT_   (N_*T_)      // 4800
#define CW_   1164         // windows per chunk -> 4 chunks
#define RC_   (CW_*L_)     // 10476 rows per chunk
#define KP_   416          // 400 padded to mult of 32 (pad zeroed in weights)

// ---- workspace layout (bytes), total ~86.8 MB ----
#define WIN_OFF   0u           // w_in  bf16 [1200,416]
#define WOUT_OFF  998400u      // w_out bf16 [400,416]
#define W1_OFF    1331200u     // w1    bf16 [1600,416]
#define W2_OFF    2662400u     // w2    bf16 [400,1600]
#define XS_OFF    3942400u     // xs    bf16 [4800,416]
#define QKV_OFF   7936000u     // qkv   bf16 [4800,1200]
#define ACC_OFF   19456000u    // acc   fp32 [4800,400]
#define OC_OFF    27136000u    // o_c   bf16 [10476,416]
#define YC_OFF    35852032u    // y_c   bf16 [10476,416]
#define HC_OFF    44568064u    // h_c   bf16 [10476,416]
#define FFC_OFF   53284096u    // ffc   bf16 [10476,1600]  end 86,807,296

using u16 = unsigned short;
using u32 = unsigned int;
using frag  = __attribute__((ext_vector_type(8))) short;   // 8 bf16
using f32x4 = __attribute__((ext_vector_type(4))) float;

__device__ __forceinline__ float bf2f(u16 u){
  return __uint_as_float(((u32)u) << 16);
}
__device__ __forceinline__ u16 f2bf(float f){
  u32 i = __float_as_uint(f);
  u32 r = (i + 0x7fffu + ((i >> 16) & 1u)) >> 16;   // RNE
  return (u16)r;
}

__global__ __launch_bounds__(256) void zero_kernel(float* __restrict__ acc, int n){
  int idx = blockIdx.x * 256 + threadIdx.x;
  if (idx < n) acc[idx] = 0.f;
}

// fp32 weight [N,K] -> bf16 [N,KP] with zeroed pad
__global__ __launch_bounds__(256) void convw_kernel(const float* __restrict__ src,
                                                    u16* __restrict__ dst,
                                                    int Nn, int K, int KPd){
  int idx = blockIdx.x * 256 + threadIdx.x;
  if (idx >= Nn * KPd) return;
  int n = idx / KPd, k = idx % KPd;
  dst[idx] = (k < K) ? f2bf(src[(size_t)n * K + k]) : (u16)0;
}

// ---- xs[n,t,:] (stride KP_) = x[n, d&15, t, d>>4] + pe[t,d] ----
__global__ __launch_bounds__(256) void embed_kernel(const float* __restrict__ x,
                                                    const float* __restrict__ pe,
                                                    u16* __restrict__ xs){
  int idx = blockIdx.x * 256 + threadIdx.x;
  if (idx >= NT_ * D_) return;
  int d  = idx % D_;
  int nt = idx / D_;
  int t  = nt % T_;
  int n  = nt / T_;
  float val = x[(((size_t)(n*C_ + (d & 15)))*T_ + t)*V_ + (d >> 4)] + pe[t*D_ + d];
  xs[(size_t)nt * KP_ + d] = f2bf(val);
}

// ---- MFMA GEMM: C[m,n] = act(sum_k A[m,k]*B[n,k] + bias[n]) ----
// A bf16 [M,lda], B bf16 [N,ldb] (K-padded, pad zero in B), C bf16 [M,ldc].
// 128x128 tile, 4 waves (2x2 of 64x64), BK=32, v_mfma_f32_16x16x32_bf16.
template<int ACT>
__global__ __launch_bounds__(256) void gemm_mfma(const u16* __restrict__ A, int lda,
                                                 const u16* __restrict__ B, int ldb,
                                                 const float* __restrict__ bias,
                                                 u16* __restrict__ C, int ldc,
                                                 int M, int Nn, int KPd){
  __shared__ u16 As[128*40];          // row stride 40 u16 = 80 B (2-way bank alias: free)
  __shared__ u16 Bs[128*40];
  const int tid  = threadIdx.x;
  const int lane = tid & 63;
  const int wv   = tid >> 6;
  const int quad = lane >> 4, l16 = lane & 15;
  const int wm   = wv & 1,   wn  = wv >> 1;
  const int m0 = blockIdx.y * 128, n0 = blockIdx.x * 128;

  f32x4 acc[4][4] = {};

  const int row0 = tid >> 2;          // 0..63
  const int sc0  = tid & 3;           // k-segment (8 bf16 each)

  for (int kt = 0; kt < KPd; kt += 32){
    #pragma unroll
    for (int h = 0; h < 2; ++h){
      int row = row0 + h*64;
      int gm = m0 + row, gn = n0 + row;
      uint4 va = make_uint4(0,0,0,0), vb = make_uint4(0,0,0,0);
      if (gm < M)  va = *(const uint4*)(A + (size_t)gm*lda + kt + sc0*8);
      if (gn < Nn) vb = *(const uint4*)(B + (size_t)gn*ldb + kt + sc0*8);
      *(uint4*)(&As[row*40 + sc0*8]) = va;
      *(uint4*)(&Bs[row*40 + sc0*8]) = vb;
    }
    __syncthreads();
    frag af[4], bfr[4];
    #pragma unroll
    for (int i = 0; i < 4; ++i){
      af[i]  = *(const frag*)(&As[(wm*64 + i*16 + l16)*40 + quad*8]);
      bfr[i] = *(const frag*)(&Bs[(wn*64 + i*16 + l16)*40 + quad*8]);
    }
    #pragma unroll
    for (int i = 0; i < 4; ++i)
      #pragma unroll
      for (int j = 0; j < 4; ++j)
        acc[i][j] = __builtin_amdgcn_mfma_f32_16x16x32_bf16(af[i], bfr[j], acc[i][j], 0, 0, 0);
    __syncthreads();
  }

  // epilogue: D layout col=lane&15, row=quad*4+reg  [guide §3, m89/m91]
  #pragma unroll
  for (int j = 0; j < 4; ++j){
    int n = n0 + wn*64 + j*16 + l16;
    float bj = (n < Nn) ? bias[n] : 0.f;
    #pragma unroll
    for (int i = 0; i < 4; ++i){
      int mbase = m0 + wm*64 + i*16 + quad*4;
      #pragma unroll
      for (int r = 0; r < 4; ++r){
        int m = mbase + r;
        if (m < M && n < Nn){
          float v = acc[i][j][r] + bj;
          if (ACT) v = 0.5f * v * (1.f + erff(v * 0.70710678f));
          C[(size_t)m*ldc + n] = f2bf(v);
        }
      }
    }
  }
}

// ---- attention for one chunk of windows; o stride KP_ ----
__global__ __launch_bounds__(256) void attn_kernel(const u16* __restrict__ qkv,
                                                   u16* __restrict__ o,
                                                   int g0){
  __shared__ float sq[L_ * 1200];
  __shared__ float sc[H_ * L_ * L_];
  __shared__ float att[H_ * L_ * L_];
  const int g = g0 + blockIdx.x;
  const int n = g / W_, w = g % W_;
  const int tid = threadIdx.x;

  for (int i = tid; i < L_ * 1200; i += 256){
    int l = i / 1200, j = i % 1200;
    sq[i] = bf2f(qkv[((size_t)(n*T_ + w + l)) * 1200 + j]);
  }
  __syncthreads();

  if (tid < H_ * L_ * L_){
    int h = tid / (L_*L_), rem = tid % (L_*L_), qi = rem / L_, ki = rem % L_;
    const float* qp = &sq[qi*1200 + h*DH_];
    const float* kp = &sq[ki*1200 + D_ + h*DH_];
    float s = 0.f;
    for (int dd = 0; dd < DH_; ++dd) s += qp[dd] * kp[dd];
    sc[tid] = s * 0.07071067811865475f;  // 1/sqrt(200)
  }
  __syncthreads();

  if (tid < H_ * L_){
    int base = tid * L_;
    float mx = -1e30f;
    for (int j = 0; j < L_; ++j) mx = fmaxf(mx, sc[base + j]);
    float sum = 0.f;
    for (int j = 0; j < L_; ++j){ float e = __expf(sc[base + j] - mx); att[base + j] = e; sum += e; }
    float inv = 1.f / sum;
    for (int j = 0; j < L_; ++j) att[base + j] *= inv;
  }
  __syncthreads();

  for (int i = tid; i < L_ * D_; i += 256){
    int l = i / D_, d = i % D_;
    int h = d / DH_;
    float a = 0.f;
    #pragma unroll
    for (int ki = 0; ki < L_; ++ki)
      a += att[h*(L_*L_) + l*L_ + ki] * sq[ki*1200 + 2*D_ + d];
    o[((size_t)blockIdx.x * L_ + l) * KP_ + d] = f2bf(a);
  }
}

// ---- LN(a_row + b_row); gather=1: a from xs window. rows stride KP_ ----
__global__ __launch_bounds__(256) void resln_kernel(const u16* a,
                                                    const u16* b,
                                                    const float* __restrict__ gam,
                                                    const float* __restrict__ bet,
                                                    u16* out,
                                                    const u16* __restrict__ xs,
                                                    int g0, int gather){
  const int r = blockIdx.x;
  const int tid = threadIdx.x;
  const u16* arow;
  if (gather){
    int g = g0 + r / L_;
    int l = r % L_;
    int n = g / W_, w = g % W_;
    arow = xs + ((size_t)(n*T_ + w + l)) * KP_;
  } else {
    arow = a + (size_t)r * KP_;
  }
  const u16* brow = b + (size_t)r * KP_;

  float v0 = bf2f(arow[tid]) + bf2f(brow[tid]);
  const bool has1 = (tid + 256) < D_;
  float v1 = has1 ? (bf2f(arow[tid + 256]) + bf2f(brow[tid + 256])) : 0.f;

  __shared__ float red[256];
  red[tid] = v0 + v1;
  __syncthreads();
  for (int s = 128; s > 0; s >>= 1){
    if (tid < s) red[tid] += red[tid + s];
    __syncthreads();
  }
  float mean = red[0] * (1.f / D_);
  __syncthreads();
  float d0 = v0 - mean;
  float d1 = has1 ? (v1 - mean) : 0.f;
  red[tid] = d0*d0 + d1*d1;
  __syncthreads();
  for (int s = 128; s > 0; s >>= 1){
    if (tid < s) red[tid] += red[tid + s];
    __syncthreads();
  }
  float rstd = rsqrtf(red[0] * (1.f / D_) + 1e-5f);
  out[(size_t)r * KP_ + tid] = f2bf(d0 * rstd * gam[tid] + bet[tid]);
  if (has1)
    out[(size_t)r * KP_ + tid + 256] = f2bf(d1 * rstd * gam[tid + 256] + bet[tid + 256]);
}

// ---- scatter-add chunk rows (stride KP_) into fp32 accumulator [N,T,D] ----
__global__ __launch_bounds__(256) void scatter_add_kernel(const u16* __restrict__ win,
                                                          float* __restrict__ acc,
                                                          int g0, int nrows){
  int idx = blockIdx.x * 256 + threadIdx.x;
  if (idx >= nrows * D_) return;
  int d = idx % D_;
  int r = idx / D_;
  int g = g0 + r / L_;
  int l = r % L_;
  int n = g / W_, w = g % W_;
  int t = (w >> 1) + l;
  atomicAdd(acc + ((size_t)(n*T_ + t)) * D_ + d, bf2f(win[(size_t)r * KP_ + d]));
}

// ---- acc[n,t,d] -> out[n,c,t,v] fp32 ----
__global__ __launch_bounds__(256) void final_kernel(const float* __restrict__ acc,
                                                    float* __restrict__ dout){
  int idx = blockIdx.x * 256 + threadIdx.x;
  if (idx >= NT_ * D_) return;
  int d  = idx % D_;
  int nt = idx / D_;
  int t  = nt % T_;
  int n  = nt / T_;
  dout[(((size_t)(n*C_ + (d & 15)))*T_ + t)*V_ + (d >> 4)] = acc[idx];
}

extern "C" void kernel_launch(void* const* d_in, const int* in_sizes, int n_in,
                              void* d_out, int out_size, void* d_ws, size_t ws_size,
                              hipStream_t stream){
  (void)in_sizes; (void)n_in; (void)out_size; (void)ws_size;
  const float* x     = (const float*)d_in[0];
  const float* pe    = (const float*)d_in[1];
  const float* w_in  = (const float*)d_in[2];
  const float* b_in  = (const float*)d_in[3];
  const float* w_out = (const float*)d_in[4];
  const float* b_out = (const float*)d_in[5];
  const float* w1    = (const float*)d_in[6];
  const float* b1    = (const float*)d_in[7];
  const float* w2    = (const float*)d_in[8];
  const float* b2    = (const float*)d_in[9];
  const float* ln1g  = (const float*)d_in[10];
  const float* ln1b  = (const float*)d_in[11];
  const float* ln2g  = (const float*)d_in[12];
  const float* ln2b  = (const float*)d_in[13];

  char* ws = (char*)d_ws;
  u16*   w_in_b  = (u16*)(ws + WIN_OFF);
  u16*   w_out_b = (u16*)(ws + WOUT_OFF);
  u16*   w1_b    = (u16*)(ws + W1_OFF);
  u16*   w2_b    = (u16*)(ws + W2_OFF);
  u16*   xs      = (u16*)(ws + XS_OFF);
  u16*   qkv     = (u16*)(ws + QKV_OFF);
  float* acc     = (float*)(ws + ACC_OFF);
  u16*   o_c     = (u16*)(ws + OC_OFF);
  u16*   y_c     = (u16*)(ws + YC_OFF);
  u16*   h_c     = (u16*)(ws + HC_OFF);
  u16*   ffc     = (u16*)(ws + FFC_OFF);

  // weight conversion fp32 -> bf16, K-padded with zeros
  convw_kernel<<<(1200*KP_ + 255)/256, 256, 0, stream>>>(w_in,  w_in_b,  1200, D_,  KP_);
  convw_kernel<<<( 400*KP_ + 255)/256, 256, 0, stream>>>(w_out, w_out_b,  400, D_,  KP_);
  convw_kernel<<<(1600*KP_ + 255)/256, 256, 0, stream>>>(w1,    w1_b,    1600, D_,  KP_);
  convw_kernel<<<( 400*FF_ + 255)/256, 256, 0, stream>>>(w2,    w2_b,     400, FF_, FF_);

  zero_kernel<<<(NT_*D_ + 255)/256, 256, 0, stream>>>(acc, NT_*D_);
  embed_kernel<<<(NT_*D_ + 255)/256, 256, 0, stream>>>(x, pe, xs);

  // qkv = xs @ w_in^T + b_in   [4800 x 1200]
  gemm_mfma<0><<<dim3((1200+127)/128, (NT_+127)/128), 256, 0, stream>>>(
      xs, KP_, w_in_b, KP_, b_in, qkv, 1200, NT_, 1200, KP_);

  for (int g0 = 0; g0 < NW_; g0 += CW_){
    int cw = NW_ - g0; if (cw > CW_) cw = CW_;
    int m = cw * L_;
    int gy = (m + 127) / 128;

    attn_kernel<<<cw, 256, 0, stream>>>(qkv, o_c, g0);

    gemm_mfma<0><<<dim3((D_+127)/128, gy), 256, 0, stream>>>(
        o_c, KP_, w_out_b, KP_, b_out, y_c, KP_, m, D_, KP_);

    resln_kernel<<<m, 256, 0, stream>>>(nullptr, y_c, ln1g, ln1b, h_c, xs, g0, 1);

    gemm_mfma<1><<<dim3((FF_+127)/128, gy), 256, 0, stream>>>(
        h_c, KP_, w1_b, KP_, b1, ffc, FF_, m, FF_, KP_);

    gemm_mfma<0><<<dim3((D_+127)/128, gy), 256, 0, stream>>>(
        ffc, FF_, w2_b, FF_, b2, y_c, KP_, m, D_, FF_);

    resln_kernel<<<m, 256, 0, stream>>>(h_c, y_c, ln2g, ln2b, h_c, nullptr, g0, 0);

    scatter_add_kernel<<<(m*D_ + 255)/256, 256, 0, stream>>>(h_c, acc, g0, m);
  }

  final_kernel<<<(NT_*D_ + 255)/256, 256, 0, stream>>>(acc, (float*)d_out);
}

// Round 8
// 853.718 us; speedup vs baseline: 4.8100x; 1.1325x over previous
//
#include <hip/hip_runtime.h>
#include <cstdint>
#include <cstddef>

// ---- problem constants ----
#define N_    16
#define C_    16
#define T_    300
#define V_    25
#define D_    400
#define H_    2
#define DH_   200
#define FF_   1600
#define L_    9
#define W_    291
#define NW_   (N_*W_)      // 4656
#define NT_   (N_*T_)      // 4800
#define CW_   1164         // windows per chunk -> 4 chunks
#define RC_   (CW_*L_)     // 10476 rows per chunk

#define KP_   416          // K-pad of D (mult of 32), zero-filled in weights
#define SD_   512          // row stride (u16) of D-wide intermediates (128-mult)
#define SQKV_ 1280         // qkv row stride / QKV N-pad
#define SFF_  1664         // ffc row stride / FFN1 N-pad (13*128)
#define MP_   10496        // padded chunk rows (82*128)
#define XSR_  4864         // padded xs rows (38*128)

// ---- workspace layout (bytes), total 96,866,304 ----
#define WIN_OFF   0u           // w_in_b  [1280][416]
#define WOUT_OFF  1064960u     // w_out_b [512][416]
#define W1_OFF    1490944u     // w1_b    [1664][416]
#define W2_OFF    2875392u     // w2_b    [512][1664]
#define XS_OFF    4579328u     // xs      [4864][512]
#define QKV_OFF   9560064u     // qkv     [4864][1280]
#define ACC_OFF   22011904u    // acc fp32[4800][400]
#define OC_OFF    29691904u    // o_c     [10496][512]
#define YC_OFF    40439808u    // y_c     [10496][512]
#define HC_OFF    51187712u    // h_c     [10496][512]
#define FFC_OFF   61935616u    // ffc     [10496][1664]  end 96,866,304

using u16 = unsigned short;
using u32 = unsigned int;
using frag  = __attribute__((ext_vector_type(8))) short;   // 8 bf16
using f32x4 = __attribute__((ext_vector_type(4))) float;

__device__ __forceinline__ float bf2f(u16 u){
  return __uint_as_float(((u32)u) << 16);
}
__device__ __forceinline__ u16 f2bf(float f){
  u32 i = __float_as_uint(f);
  u32 r = (i + 0x7fffu + ((i >> 16) & 1u)) >> 16;   // RNE
  return (u16)r;
}

__global__ __launch_bounds__(256) void zero_kernel(float* __restrict__ acc, int n){
  int idx = blockIdx.x * 256 + threadIdx.x;
  if (idx < n) acc[idx] = 0.f;
}

// fp32 [sN,sK] -> bf16 [dN,dK], zero-filled pad
__global__ __launch_bounds__(256) void convw_kernel(const float* __restrict__ src,
                                                    u16* __restrict__ dst,
                                                    int dN, int dK, int sN, int sK){
  int idx = blockIdx.x * 256 + threadIdx.x;
  if (idx >= dN * dK) return;
  int n = idx / dK, k = idx % dK;
  dst[idx] = (n < sN && k < sK) ? f2bf(src[(size_t)n * sK + k]) : (u16)0;
}

// ---- xs[nt, d] (stride SD_) = x[n, d&15, t, d>>4] + pe[t,d] ----
__global__ __launch_bounds__(256) void embed_kernel(const float* __restrict__ x,
                                                    const float* __restrict__ pe,
                                                    u16* __restrict__ xs){
  int idx = blockIdx.x * 256 + threadIdx.x;
  if (idx >= NT_ * D_) return;
  int d  = idx % D_;
  int nt = idx / D_;
  int t  = nt % T_;
  int n  = nt / T_;
  float val = x[(((size_t)(n*C_ + (d & 15)))*T_ + t)*V_ + (d >> 4)] + pe[t*D_ + d];
  xs[(size_t)nt * SD_ + d] = f2bf(val);
}

// ---- MFMA GEMM, m97-style: global_load_lds(16B) staging, swizzled LDS,
//      XCD-aware block decode. All A/B tile reads exact-fit (buffers padded).
//      C[m,n] = act(sum_k A[m,k]*B[n,k] + bias[n]), store-guarded by M/Nn.
template<int ACT>
__global__ __launch_bounds__(256) void gemm_mfma(const u16* __restrict__ A, int lda,
                                                 const u16* __restrict__ B, int ldb,
                                                 const float* __restrict__ bias,
                                                 u16* __restrict__ C, int ldc,
                                                 int M, int Nn, int KPd,
                                                 int gx, int gy){
  __shared__ u16 As[128*32];     // 128 rows x 64B, xor-swizzled slots
  __shared__ u16 Bs[128*32];
  // XCD-aware decode: id%8 = XCD owns M-tile rows by%8==c, all N-tiles -> A reuse in L2
  int id = blockIdx.x;
  int c  = id & 7, t = id >> 3;
  int bx = t % gx;
  int by = (t / gx) * 8 + c;
  if (by >= gy) return;
  const int m0 = by * 128, n0 = bx * 128;

  const int tid  = threadIdx.x;
  const int lane = tid & 63;
  const int wv   = tid >> 6;
  const int quad = lane >> 4, l16 = lane & 15;
  const int wm   = wv & 1,   wn  = wv >> 1;

  // staging: lane lambda -> LDS row r4=lane>>2 (within 16-row group), slot lane&3,
  // which holds global k-segment s = (lane&3) ^ ((lane>>3)&3)  [xor swizzle]
  const int r4 = lane >> 2;
  const int sseg = (lane & 3) ^ ((lane >> 3) & 3);
  const u16* Ag = A + (size_t)(m0 + wv*32 + r4) * lda + sseg*8;
  const u16* Bg = B + (size_t)(n0 + wv*32 + r4) * ldb + sseg*8;
  u16* AsW = &As[(wv*32)*32];
  u16* BsW = &Bs[(wv*32)*32];

  f32x4 acc[4][4] = {};
  const int sa = quad ^ ((l16 >> 1) & 3);   // read-side swizzled slot

  for (int kt = 0; kt < KPd; kt += 32){
    __builtin_amdgcn_global_load_lds(
        (const __attribute__((address_space(1))) void*)(Ag + kt),
        (__attribute__((address_space(3))) void*)(AsW), 16, 0, 0);
    __builtin_amdgcn_global_load_lds(
        (const __attribute__((address_space(1))) void*)(Ag + kt + (size_t)16*lda),
        (__attribute__((address_space(3))) void*)(AsW + 16*32), 16, 0, 0);
    __builtin_amdgcn_global_load_lds(
        (const __attribute__((address_space(1))) void*)(Bg + kt),
        (__attribute__((address_space(3))) void*)(BsW), 16, 0, 0);
    __builtin_amdgcn_global_load_lds(
        (const __attribute__((address_space(1))) void*)(Bg + kt + (size_t)16*ldb),
        (__attribute__((address_space(3))) void*)(BsW + 16*32), 16, 0, 0);
    __syncthreads();

    frag af[4], bfr[4];
    #pragma unroll
    for (int i = 0; i < 4; ++i){
      af[i]  = *(const frag*)(&As[(wm*64 + i*16 + l16)*32 + sa*8]);
      bfr[i] = *(const frag*)(&Bs[(wn*64 + i*16 + l16)*32 + sa*8]);
    }
    #pragma unroll
    for (int i = 0; i < 4; ++i)
      #pragma unroll
      for (int j = 0; j < 4; ++j)
        acc[i][j] = __builtin_amdgcn_mfma_f32_16x16x32_bf16(af[i], bfr[j], acc[i][j], 0, 0, 0);
    __syncthreads();
  }

  // epilogue: D layout col=lane&15, row=quad*4+reg
  #pragma unroll
  for (int j = 0; j < 4; ++j){
    int n = n0 + wn*64 + j*16 + l16;
    float bj = (n < Nn) ? bias[n] : 0.f;
    #pragma unroll
    for (int i = 0; i < 4; ++i){
      int mbase = m0 + wm*64 + i*16 + quad*4;
      #pragma unroll
      for (int r = 0; r < 4; ++r){
        int m = mbase + r;
        if (m < M && n < Nn){
          float v = acc[i][j][r] + bj;
          if (ACT) v = 0.5f * v * (1.f + erff(v * 0.70710678f));
          C[(size_t)m*ldc + n] = f2bf(v);
        }
      }
    }
  }
}

// ---- attention for one chunk of windows; qkv stride SQKV_, o stride SD_ ----
__global__ __launch_bounds__(256) void attn_kernel(const u16* __restrict__ qkv,
                                                   u16* __restrict__ o,
                                                   int g0){
  __shared__ float sq[L_ * 1200];
  __shared__ float sc[H_ * L_ * L_];
  __shared__ float att[H_ * L_ * L_];
  const int g = g0 + blockIdx.x;
  const int n = g / W_, w = g % W_;
  const int tid = threadIdx.x;

  for (int i = tid; i < L_ * 1200; i += 256){
    int l = i / 1200, j = i % 1200;
    sq[i] = bf2f(qkv[((size_t)(n*T_ + w + l)) * SQKV_ + j]);
  }
  __syncthreads();

  if (tid < H_ * L_ * L_){
    int h = tid / (L_*L_), rem = tid % (L_*L_), qi = rem / L_, ki = rem % L_;
    const float* qp = &sq[qi*1200 + h*DH_];
    const float* kp = &sq[ki*1200 + D_ + h*DH_];
    float s = 0.f;
    for (int dd = 0; dd < DH_; ++dd) s += qp[dd] * kp[dd];
    sc[tid] = s * 0.07071067811865475f;  // 1/sqrt(200)
  }
  __syncthreads();

  if (tid < H_ * L_){
    int base = tid * L_;
    float mx = -1e30f;
    for (int j = 0; j < L_; ++j) mx = fmaxf(mx, sc[base + j]);
    float sum = 0.f;
    for (int j = 0; j < L_; ++j){ float e = __expf(sc[base + j] - mx); att[base + j] = e; sum += e; }
    float inv = 1.f / sum;
    for (int j = 0; j < L_; ++j) att[base + j] *= inv;
  }
  __syncthreads();

  for (int i = tid; i < L_ * D_; i += 256){
    int l = i / D_, d = i % D_;
    int h = d / DH_;
    float a = 0.f;
    #pragma unroll
    for (int ki = 0; ki < L_; ++ki)
      a += att[h*(L_*L_) + l*L_ + ki] * sq[ki*1200 + 2*D_ + d];
    o[((size_t)blockIdx.x * L_ + l) * SD_ + d] = f2bf(a);
  }
}

// ---- LN(a_row + b_row); gather=1: a from xs window. rows stride SD_ ----
__global__ __launch_bounds__(256) void resln_kernel(const u16* a,
                                                    const u16* b,
                                                    const float* __restrict__ gam,
                                                    const float* __restrict__ bet,
                                                    u16* out,
                                                    const u16* __restrict__ xs,
                                                    int g0, int gather){
  const int r = blockIdx.x;
  const int tid = threadIdx.x;
  const u16* arow;
  if (gather){
    int g = g0 + r / L_;
    int l = r % L_;
    int n = g / W_, w = g % W_;
    arow = xs + ((size_t)(n*T_ + w + l)) * SD_;
  } else {
    arow = a + (size_t)r * SD_;
  }
  const u16* brow = b + (size_t)r * SD_;

  float v0 = bf2f(arow[tid]) + bf2f(brow[tid]);
  const bool has1 = (tid + 256) < D_;
  float v1 = has1 ? (bf2f(arow[tid + 256]) + bf2f(brow[tid + 256])) : 0.f;

  __shared__ float red[256];
  red[tid] = v0 + v1;
  __syncthreads();
  for (int s = 128; s > 0; s >>= 1){
    if (tid < s) red[tid] += red[tid + s];
    __syncthreads();
  }
  float mean = red[0] * (1.f / D_);
  __syncthreads();
  float d0 = v0 - mean;
  float d1 = has1 ? (v1 - mean) : 0.f;
  red[tid] = d0*d0 + d1*d1;
  __syncthreads();
  for (int s = 128; s > 0; s >>= 1){
    if (tid < s) red[tid] += red[tid + s];
    __syncthreads();
  }
  float rstd = rsqrtf(red[0] * (1.f / D_) + 1e-5f);
  out[(size_t)r * SD_ + tid] = f2bf(d0 * rstd * gam[tid] + bet[tid]);
  if (has1)
    out[(size_t)r * SD_ + tid + 256] = f2bf(d1 * rstd * gam[tid + 256] + bet[tid + 256]);
}

// ---- scatter-add chunk rows (stride SD_) into fp32 accumulator [N,T,D] ----
__global__ __launch_bounds__(256) void scatter_add_kernel(const u16* __restrict__ win,
                                                          float* __restrict__ acc,
                                                          int g0, int nrows){
  int idx = blockIdx.x * 256 + threadIdx.x;
  if (idx >= nrows * D_) return;
  int d = idx % D_;
  int r = idx / D_;
  int g = g0 + r / L_;
  int l = r % L_;
  int n = g / W_, w = g % W_;
  int t = (w >> 1) + l;
  atomicAdd(acc + ((size_t)(n*T_ + t)) * D_ + d, bf2f(win[(size_t)r * SD_ + d]));
}

// ---- acc[n,t,d] -> out[n,c,t,v] fp32 ----
__global__ __launch_bounds__(256) void final_kernel(const float* __restrict__ acc,
                                                    float* __restrict__ dout){
  int idx = blockIdx.x * 256 + threadIdx.x;
  if (idx >= NT_ * D_) return;
  int d  = idx % D_;
  int nt = idx / D_;
  int t  = nt % T_;
  int n  = nt / T_;
  dout[(((size_t)(n*C_ + (d & 15)))*T_ + t)*V_ + (d >> 4)] = acc[idx];
}

extern "C" void kernel_launch(void* const* d_in, const int* in_sizes, int n_in,
                              void* d_out, int out_size, void* d_ws, size_t ws_size,
                              hipStream_t stream){
  (void)in_sizes; (void)n_in; (void)out_size; (void)ws_size;
  const float* x     = (const float*)d_in[0];
  const float* pe    = (const float*)d_in[1];
  const float* w_in  = (const float*)d_in[2];
  const float* b_in  = (const float*)d_in[3];
  const float* w_out = (const float*)d_in[4];
  const float* b_out = (const float*)d_in[5];
  const float* w1    = (const float*)d_in[6];
  const float* b1    = (const float*)d_in[7];
  const float* w2    = (const float*)d_in[8];
  const float* b2    = (const float*)d_in[9];
  const float* ln1g  = (const float*)d_in[10];
  const float* ln1b  = (const float*)d_in[11];
  const float* ln2g  = (const float*)d_in[12];
  const float* ln2b  = (const float*)d_in[13];

  char* ws = (char*)d_ws;
  u16*   w_in_b  = (u16*)(ws + WIN_OFF);
  u16*   w_out_b = (u16*)(ws + WOUT_OFF);
  u16*   w1_b    = (u16*)(ws + W1_OFF);
  u16*   w2_b    = (u16*)(ws + W2_OFF);
  u16*   xs      = (u16*)(ws + XS_OFF);
  u16*   qkv     = (u16*)(ws + QKV_OFF);
  float* acc     = (float*)(ws + ACC_OFF);
  u16*   o_c     = (u16*)(ws + OC_OFF);
  u16*   y_c     = (u16*)(ws + YC_OFF);
  u16*   h_c     = (u16*)(ws + HC_OFF);
  u16*   ffc     = (u16*)(ws + FFC_OFF);

  // weight conversion fp32 -> bf16, padded with zeros to tile multiples
  convw_kernel<<<(1280*KP_  + 255)/256, 256, 0, stream>>>(w_in,  w_in_b,  1280, KP_, 1200, D_);
  convw_kernel<<<( 512*KP_  + 255)/256, 256, 0, stream>>>(w_out, w_out_b,  512, KP_,  400, D_);
  convw_kernel<<<(1664*KP_  + 255)/256, 256, 0, stream>>>(w1,    w1_b,    1664, KP_, 1600, D_);
  convw_kernel<<<( 512*SFF_ + 255)/256, 256, 0, stream>>>(w2,    w2_b,     512, SFF_, 400, FF_);

  zero_kernel<<<(NT_*D_ + 255)/256, 256, 0, stream>>>(acc, NT_*D_);
  embed_kernel<<<(NT_*D_ + 255)/256, 256, 0, stream>>>(x, pe, xs);

  // qkv = xs @ w_in^T + b_in   [4800 x 1200], grids XCD-decoded (gx, gy, gy8)
  {
    int gx = SQKV_/128, gy = (NT_ + 127)/128, gy8 = (gy + 7) & ~7;
    gemm_mfma<0><<<gx*gy8, 256, 0, stream>>>(
        xs, SD_, w_in_b, KP_, b_in, qkv, SQKV_, NT_, 1200, KP_, gx, gy);
  }

  const int gyc = (RC_ + 127)/128, gyc8 = (gyc + 7) & ~7;   // 82, 88

  for (int g0 = 0; g0 < NW_; g0 += CW_){
    attn_kernel<<<CW_, 256, 0, stream>>>(qkv, o_c, g0);

    gemm_mfma<0><<<(SD_/128)*gyc8, 256, 0, stream>>>(
        o_c, SD_, w_out_b, KP_, b_out, y_c, SD_, RC_, D_, KP_, SD_/128, gyc);

    resln_kernel<<<RC_, 256, 0, stream>>>(nullptr, y_c, ln1g, ln1b, h_c, xs, g0, 1);

    gemm_mfma<1><<<(SFF_/128)*gyc8, 256, 0, stream>>>(
        h_c, SD_, w1_b, KP_, b1, ffc, SFF_, RC_, FF_, KP_, SFF_/128, gyc);

    gemm_mfma<0><<<(SD_/128)*gyc8, 256, 0, stream>>>(
        ffc, SFF_, w2_b, SFF_, b2, y_c, SD_, RC_, D_, FF_, SD_/128, gyc);

    resln_kernel<<<RC_, 256, 0, stream>>>(h_c, y_c, ln2g, ln2b, h_c, nullptr, g0, 0);

    scatter_add_kernel<<<(RC_*D_ + 255)/256, 256, 0, stream>>>(h_c, acc, g0, RC_);
  }

  final_kernel<<<(NT_*D_ + 255)/256, 256, 0, stream>>>(acc, (float*)d_out);
}

// Round 9
// 730.150 us; speedup vs baseline: 5.6241x; 1.1692x over previous
//
#include <hip/hip_runtime.h>
#include <cstdint>
#include <cstddef>

// ---- problem constants ----
#define N_    16
#define C_    16
#define T_    300
#define V_    25
#define D_    400
#define H_    2
#define DH_   200
#define FF_   1600
#define L_    9
#define W_    291
#define NW_   (N_*W_)      // 4656
#define NT_   (N_*T_)      // 4800
#define CW_   1552         // windows per chunk -> 3 chunks (exact)
#define RC_   (CW_*L_)     // 13968 rows per chunk
#define RCP_  14080        // padded chunk rows (110*128)

#define KP_   416          // K-pad of D (mult of 32), zero-filled in weights
#define SD_   512          // row stride (u16) of D-wide intermediates
#define SQKV_ 1280         // qkv row stride / QKV N-pad
#define SFF_  1664         // ffc row stride / FFN1 N-pad (13*128)

// ---- workspace layout (bytes), total 119,803,904 (ws >= 129 MB proven R2) ----
#define WIN_OFF   0u           // w_in_b  [1280][416]
#define WOUT_OFF  1064960u     // w_out_b [512][416]
#define W1_OFF    1490944u     // w1_b    [1664][416]
#define W2_OFF    2875392u     // w2_b    [512][1664]
#define XS_OFF    4579328u     // xs      [4864][512]
#define QKV_OFF   9560064u     // qkv     [4864][1280]
#define ACC_OFF   22011904u    // acc fp32[4800][400]
#define OC_OFF    29691904u    // o_c     [14080][512]
#define YC_OFF    44109824u    // y_c     [14080][512]
#define HC_OFF    58527744u    // h_c     [14080][512]
#define FFC_OFF   72945664u    // ffc     [14080][1664]  end 119,803,904

using u16 = unsigned short;
using u32 = unsigned int;
using frag  = __attribute__((ext_vector_type(8))) short;   // 8 bf16
using f32x4 = __attribute__((ext_vector_type(4))) float;

__device__ __forceinline__ float bf2f(u16 u){
  return __uint_as_float(((u32)u) << 16);
}
__device__ __forceinline__ u16 f2bf(float f){
  u32 i = __float_as_uint(f);
  u32 r = (i + 0x7fffu + ((i >> 16) & 1u)) >> 16;   // RNE
  return (u16)r;
}

__global__ __launch_bounds__(256) void zero_kernel(float* __restrict__ acc, int n){
  int idx = blockIdx.x * 256 + threadIdx.x;
  if (idx < n) acc[idx] = 0.f;
}

// fp32 [sN,sK] -> bf16 [dN,dK], zero-filled pad
__global__ __launch_bounds__(256) void convw_kernel(const float* __restrict__ src,
                                                    u16* __restrict__ dst,
                                                    int dN, int dK, int sN, int sK){
  int idx = blockIdx.x * 256 + threadIdx.x;
  if (idx >= dN * dK) return;
  int n = idx / dK, k = idx % dK;
  dst[idx] = (n < sN && k < sK) ? f2bf(src[(size_t)n * sK + k]) : (u16)0;
}

// ---- xs[nt, d] (stride SD_) = x[n, d&15, t, d>>4] + pe[t,d] ----
__global__ __launch_bounds__(256) void embed_kernel(const float* __restrict__ x,
                                                    const float* __restrict__ pe,
                                                    u16* __restrict__ xs){
  int idx = blockIdx.x * 256 + threadIdx.x;
  if (idx >= NT_ * D_) return;
  int d  = idx % D_;
  int nt = idx / D_;
  int t  = nt % T_;
  int n  = nt / T_;
  float val = x[(((size_t)(n*C_ + (d & 15)))*T_ + t)*V_ + (d >> 4)] + pe[t*D_ + d];
  xs[(size_t)nt * SD_ + d] = f2bf(val);
}

// ---- MFMA GEMM: global_load_lds(16B) DOUBLE-BUFFERED, swizzled LDS, XCD decode.
//      C[m,n] = act(sum_k A[m,k]*B[n,k] + bias[n]); A/B reads exact-fit (padded).
template<int ACT>
__global__ __launch_bounds__(256) void gemm_mfma(const u16* __restrict__ A, int lda,
                                                 const u16* __restrict__ B, int ldb,
                                                 const float* __restrict__ bias,
                                                 u16* __restrict__ C, int ldc,
                                                 int M, int Nn, int KPd,
                                                 int gx, int gy){
  __shared__ u16 As[2][128*32];
  __shared__ u16 Bs[2][128*32];
  int id = blockIdx.x;
  int c  = id & 7, t = id >> 3;
  int bx = t % gx;
  int by = (t / gx) * 8 + c;           // XCD c owns M-tile residue class
  if (by >= gy) return;
  const int m0 = by * 128, n0 = bx * 128;

  const int tid  = threadIdx.x;
  const int lane = tid & 63;
  const int wv   = tid >> 6;
  const int quad = lane >> 4, l16 = lane & 15;
  const int wm   = wv & 1,   wn  = wv >> 1;

  const int r4 = lane >> 2;
  const int sseg = (lane & 3) ^ ((lane >> 3) & 3);     // xor-swizzled k-segment
  const u16* Ag = A + (size_t)(m0 + wv*32 + r4) * lda + sseg*8;
  const u16* Bg = B + (size_t)(n0 + wv*32 + r4) * ldb + sseg*8;

  f32x4 acc[4][4] = {};
  const int sa = quad ^ ((l16 >> 1) & 3);              // read-side slot

  auto stage = [&](int buf, int kt){
    u16* AsW = &As[buf][(wv*32)*32];
    u16* BsW = &Bs[buf][(wv*32)*32];
    __builtin_amdgcn_global_load_lds(
        (const __attribute__((address_space(1))) void*)(Ag + kt),
        (__attribute__((address_space(3))) void*)(AsW), 16, 0, 0);
    __builtin_amdgcn_global_load_lds(
        (const __attribute__((address_space(1))) void*)(Ag + kt + (size_t)16*lda),
        (__attribute__((address_space(3))) void*)(AsW + 16*32), 16, 0, 0);
    __builtin_amdgcn_global_load_lds(
        (const __attribute__((address_space(1))) void*)(Bg + kt),
        (__attribute__((address_space(3))) void*)(BsW), 16, 0, 0);
    __builtin_amdgcn_global_load_lds(
        (const __attribute__((address_space(1))) void*)(Bg + kt + (size_t)16*ldb),
        (__attribute__((address_space(3))) void*)(BsW + 16*32), 16, 0, 0);
  };

  const int nit = KPd >> 5;
  stage(0, 0);
  for (int it = 0; it < nit; ++it){
    __syncthreads();                         // drains buf[it&1] loads (vmcnt)
    if (it + 1 < nit) stage((it + 1) & 1, (it + 1) << 5);   // prefetch in flight
    const int buf = it & 1;
    frag af[4], bfr[4];
    #pragma unroll
    for (int i = 0; i < 4; ++i){
      af[i]  = *(const frag*)(&As[buf][(wm*64 + i*16 + l16)*32 + sa*8]);
      bfr[i] = *(const frag*)(&Bs[buf][(wn*64 + i*16 + l16)*32 + sa*8]);
    }
    #pragma unroll
    for (int i = 0; i < 4; ++i)
      #pragma unroll
      for (int j = 0; j < 4; ++j)
        acc[i][j] = __builtin_amdgcn_mfma_f32_16x16x32_bf16(af[i], bfr[j], acc[i][j], 0, 0, 0);
  }

  // epilogue: D layout col=lane&15, row=quad*4+reg
  #pragma unroll
  for (int j = 0; j < 4; ++j){
    int n = n0 + wn*64 + j*16 + l16;
    float bj = (n < Nn) ? bias[n] : 0.f;
    #pragma unroll
    for (int i = 0; i < 4; ++i){
      int mbase = m0 + wm*64 + i*16 + quad*4;
      #pragma unroll
      for (int r = 0; r < 4; ++r){
        int m = mbase + r;
        if (m < M && n < Nn){
          float v = acc[i][j][r] + bj;
          if (ACT) v = 0.5f * v * (1.f + erff(v * 0.70710678f));
          C[(size_t)m*ldc + n] = f2bf(v);
        }
      }
    }
  }
}

// ---- attention for one chunk of windows; qkv stride SQKV_, o stride SD_ ----
__global__ __launch_bounds__(256) void attn_kernel(const u16* __restrict__ qkv,
                                                   u16* __restrict__ o,
                                                   int g0){
  __shared__ float sq[L_ * 1200];
  __shared__ float sc[H_ * L_ * L_];
  __shared__ float att[H_ * L_ * L_];
  const int g = g0 + blockIdx.x;
  const int n = g / W_, w = g % W_;
  const int tid = threadIdx.x;

  for (int i = tid; i < L_ * 1200; i += 256){
    int l = i / 1200, j = i % 1200;
    sq[i] = bf2f(qkv[((size_t)(n*T_ + w + l)) * SQKV_ + j]);
  }
  __syncthreads();

  if (tid < H_ * L_ * L_){
    int h = tid / (L_*L_), rem = tid % (L_*L_), qi = rem / L_, ki = rem % L_;
    const float* qp = &sq[qi*1200 + h*DH_];
    const float* kp = &sq[ki*1200 + D_ + h*DH_];
    float s = 0.f;
    for (int dd = 0; dd < DH_; ++dd) s += qp[dd] * kp[dd];
    sc[tid] = s * 0.07071067811865475f;  // 1/sqrt(200)
  }
  __syncthreads();

  if (tid < H_ * L_){
    int base = tid * L_;
    float mx = -1e30f;
    for (int j = 0; j < L_; ++j) mx = fmaxf(mx, sc[base + j]);
    float sum = 0.f;
    for (int j = 0; j < L_; ++j){ float e = __expf(sc[base + j] - mx); att[base + j] = e; sum += e; }
    float inv = 1.f / sum;
    for (int j = 0; j < L_; ++j) att[base + j] *= inv;
  }
  __syncthreads();

  for (int i = tid; i < L_ * D_; i += 256){
    int l = i / D_, d = i % D_;
    int h = d / DH_;
    float a = 0.f;
    #pragma unroll
    for (int ki = 0; ki < L_; ++ki)
      a += att[h*(L_*L_) + l*L_ + ki] * sq[ki*1200 + 2*D_ + d];
    o[((size_t)blockIdx.x * L_ + l) * SD_ + d] = f2bf(a);
  }
}

// ---- LN(a_row + b_row); gather=1: a from xs window. rows stride SD_ ----
__global__ __launch_bounds__(256) void resln_kernel(const u16* a,
                                                    const u16* b,
                                                    const float* __restrict__ gam,
                                                    const float* __restrict__ bet,
                                                    u16* out,
                                                    const u16* __restrict__ xs,
                                                    int g0, int gather){
  const int r = blockIdx.x;
  const int tid = threadIdx.x;
  const u16* arow;
  if (gather){
    int g = g0 + r / L_;
    int l = r % L_;
    int n = g / W_, w = g % W_;
    arow = xs + ((size_t)(n*T_ + w + l)) * SD_;
  } else {
    arow = a + (size_t)r * SD_;
  }
  const u16* brow = b + (size_t)r * SD_;

  float v0 = bf2f(arow[tid]) + bf2f(brow[tid]);
  const bool has1 = (tid + 256) < D_;
  float v1 = has1 ? (bf2f(arow[tid + 256]) + bf2f(brow[tid + 256])) : 0.f;

  __shared__ float red[256];
  red[tid] = v0 + v1;
  __syncthreads();
  for (int s = 128; s > 0; s >>= 1){
    if (tid < s) red[tid] += red[tid + s];
    __syncthreads();
  }
  float mean = red[0] * (1.f / D_);
  __syncthreads();
  float d0 = v0 - mean;
  float d1 = has1 ? (v1 - mean) : 0.f;
  red[tid] = d0*d0 + d1*d1;
  __syncthreads();
  for (int s = 128; s > 0; s >>= 1){
    if (tid < s) red[tid] += red[tid + s];
    __syncthreads();
  }
  float rstd = rsqrtf(red[0] * (1.f / D_) + 1e-5f);
  out[(size_t)r * SD_ + tid] = f2bf(d0 * rstd * gam[tid] + bet[tid]);
  if (has1)
    out[(size_t)r * SD_ + tid + 256] = f2bf(d1 * rstd * gam[tid + 256] + bet[tid + 256]);
}

// ---- scatter-add chunk rows (stride SD_) into fp32 accumulator [N,T,D] ----
__global__ __launch_bounds__(256) void scatter_add_kernel(const u16* __restrict__ win,
                                                          float* __restrict__ acc,
                                                          int g0, int nrows){
  int idx = blockIdx.x * 256 + threadIdx.x;
  if (idx >= nrows * D_) return;
  int d = idx % D_;
  int r = idx / D_;
  int g = g0 + r / L_;
  int l = r % L_;
  int n = g / W_, w = g % W_;
  int t = (w >> 1) + l;
  atomicAdd(acc + ((size_t)(n*T_ + t)) * D_ + d, bf2f(win[(size_t)r * SD_ + d]));
}

// ---- acc[n,t,d] -> out[n,c,t,v] fp32 ----
__global__ __launch_bounds__(256) void final_kernel(const float* __restrict__ acc,
                                                    float* __restrict__ dout){
  int idx = blockIdx.x * 256 + threadIdx.x;
  if (idx >= NT_ * D_) return;
  int d  = idx % D_;
  int nt = idx / D_;
  int t  = nt % T_;
  int n  = nt / T_;
  dout[(((size_t)(n*C_ + (d & 15)))*T_ + t)*V_ + (d >> 4)] = acc[idx];
}

extern "C" void kernel_launch(void* const* d_in, const int* in_sizes, int n_in,
                              void* d_out, int out_size, void* d_ws, size_t ws_size,
                              hipStream_t stream){
  (void)in_sizes; (void)n_in; (void)out_size; (void)ws_size;
  const float* x     = (const float*)d_in[0];
  const float* pe    = (const float*)d_in[1];
  const float* w_in  = (const float*)d_in[2];
  const float* b_in  = (const float*)d_in[3];
  const float* w_out = (const float*)d_in[4];
  const float* b_out = (const float*)d_in[5];
  const float* w1    = (const float*)d_in[6];
  const float* b1    = (const float*)d_in[7];
  const float* w2    = (const float*)d_in[8];
  const float* b2    = (const float*)d_in[9];
  const float* ln1g  = (const float*)d_in[10];
  const float* ln1b  = (const float*)d_in[11];
  const float* ln2g  = (const float*)d_in[12];
  const float* ln2b  = (const float*)d_in[13];

  char* ws = (char*)d_ws;
  u16*   w_in_b  = (u16*)(ws + WIN_OFF);
  u16*   w_out_b = (u16*)(ws + WOUT_OFF);
  u16*   w1_b    = (u16*)(ws + W1_OFF);
  u16*   w2_b    = (u16*)(ws + W2_OFF);
  u16*   xs      = (u16*)(ws + XS_OFF);
  u16*   qkv     = (u16*)(ws + QKV_OFF);
  float* acc     = (float*)(ws + ACC_OFF);
  u16*   o_c     = (u16*)(ws + OC_OFF);
  u16*   y_c     = (u16*)(ws + YC_OFF);
  u16*   h_c     = (u16*)(ws + HC_OFF);
  u16*   ffc     = (u16*)(ws + FFC_OFF);

  // weight conversion fp32 -> bf16, padded with zeros to tile multiples
  convw_kernel<<<(1280*KP_  + 255)/256, 256, 0, stream>>>(w_in,  w_in_b,  1280, KP_, 1200, D_);
  convw_kernel<<<( 512*KP_  + 255)/256, 256, 0, stream>>>(w_out, w_out_b,  512, KP_,  400, D_);
  convw_kernel<<<(1664*KP_  + 255)/256, 256, 0, stream>>>(w1,    w1_b,    1664, KP_, 1600, D_);
  convw_kernel<<<( 512*SFF_ + 255)/256, 256, 0, stream>>>(w2,    w2_b,     512, SFF_, 400, FF_);

  zero_kernel<<<(NT_*D_ + 255)/256, 256, 0, stream>>>(acc, NT_*D_);
  embed_kernel<<<(NT_*D_ + 255)/256, 256, 0, stream>>>(x, pe, xs);

  // qkv = xs @ w_in^T + b_in   [4800 x 1200]
  {
    int gx = SQKV_/128, gy = (NT_ + 127)/128, gy8 = (gy + 7) & ~7;
    gemm_mfma<0><<<gx*gy8, 256, 0, stream>>>(
        xs, SD_, w_in_b, KP_, b_in, qkv, SQKV_, NT_, 1200, KP_, gx, gy);
  }

  const int gyc = RCP_/128, gyc8 = (gyc + 7) & ~7;   // 110, 112

  for (int g0 = 0; g0 < NW_; g0 += CW_){
    attn_kernel<<<CW_, 256, 0, stream>>>(qkv, o_c, g0);

    gemm_mfma<0><<<(SD_/128)*gyc8, 256, 0, stream>>>(
        o_c, SD_, w_out_b, KP_, b_out, y_c, SD_, RC_, D_, KP_, SD_/128, gyc);

    resln_kernel<<<RC_, 256, 0, stream>>>(nullptr, y_c, ln1g, ln1b, h_c, xs, g0, 1);

    gemm_mfma<1><<<(SFF_/128)*gyc8, 256, 0, stream>>>(
        h_c, SD_, w1_b, KP_, b1, ffc, SFF_, RC_, FF_, KP_, SFF_/128, gyc);

    gemm_mfma<0><<<(SD_/128)*gyc8, 256, 0, stream>>>(
        ffc, SFF_, w2_b, SFF_, b2, y_c, SD_, RC_, D_, FF_, SD_/128, gyc);

    resln_kernel<<<RC_, 256, 0, stream>>>(h_c, y_c, ln2g, ln2b, h_c, nullptr, g0, 0);

    scatter_add_kernel<<<(RC_*D_ + 255)/256, 256, 0, stream>>>(h_c, acc, g0, RC_);
  }

  final_kernel<<<(NT_*D_ + 255)/256, 256, 0, stream>>>(acc, (float*)d_out);
}

// Round 10
// 668.450 us; speedup vs baseline: 6.1432x; 1.0923x over previous
//
#include <hip/hip_runtime.h>
#include <cstdint>
#include <cstddef>

// ---- problem constants ----
#define N_    16
#define C_    16
#define T_    300
#define V_    25
#define D_    400
#define H_    2
#define DH_   200
#define FF_   1600
#define L_    9
#define W_    291
#define NW_   (N_*W_)      // 4656
#define NT_   (N_*T_)      // 4800
#define CW_   1552         // windows per chunk -> 3 chunks
#define RC_   (CW_*L_)     // 13968 rows per chunk
#define RCP_  14080        // padded chunk rows (110*128)

#define KP_   416          // K-pad of D (mult of 32), zero-filled in weights
#define SD_   512          // row stride of D-wide intermediates
#define SQKV_ 1280         // qkv row stride / QKV N-pad
#define SFF_  1664         // ffc row stride / FFN1 N-pad

// ---- workspace layout (bytes), total 119,803,904 ----
#define WIN_OFF   0u
#define WOUT_OFF  1064960u
#define W1_OFF    1490944u
#define W2_OFF    2875392u
#define XS_OFF    4579328u
#define QKV_OFF   9560064u
#define ACC_OFF   22011904u
#define OC_OFF    29691904u
#define YC_OFF    44109824u
#define HC_OFF    58527744u
#define FFC_OFF   72945664u

// s_waitcnt immediates (gfx9 packing): vmcnt[3:0]|expcnt<<4|lgkm<<8|vmcnt[5:4]<<14
#define WAIT_VM8   0xF78    // vmcnt<=8, lgkm/exp don't-care
#define WAIT_VM0   0xF70    // vmcnt<=0
#define WAIT_LGKM0 0xC07F   // lgkmcnt<=0, vmcnt/exp don't-care

using u16 = unsigned short;
using u32 = unsigned int;
using frag  = __attribute__((ext_vector_type(8))) short;   // 8 bf16
using f32x4 = __attribute__((ext_vector_type(4))) float;

__device__ __forceinline__ float bf2f(u16 u){
  return __uint_as_float(((u32)u) << 16);
}
__device__ __forceinline__ u16 f2bf(float f){
  u32 i = __float_as_uint(f);
  u32 r = (i + 0x7fffu + ((i >> 16) & 1u)) >> 16;   // RNE
  return (u16)r;
}

__global__ __launch_bounds__(256) void zero_kernel(float* __restrict__ acc, int n){
  int idx = blockIdx.x * 256 + threadIdx.x;
  if (idx < n) acc[idx] = 0.f;
}

// fp32 [sN,sK] -> bf16 [dN,dK], zero-filled pad
__global__ __launch_bounds__(256) void convw_kernel(const float* __restrict__ src,
                                                    u16* __restrict__ dst,
                                                    int dN, int dK, int sN, int sK){
  int idx = blockIdx.x * 256 + threadIdx.x;
  if (idx >= dN * dK) return;
  int n = idx / dK, k = idx % dK;
  dst[idx] = (n < sN && k < sK) ? f2bf(src[(size_t)n * sK + k]) : (u16)0;
}

// ---- xs[nt, d] (stride SD_) = x[n, d&15, t, d>>4] + pe[t,d] ----
__global__ __launch_bounds__(256) void embed_kernel(const float* __restrict__ x,
                                                    const float* __restrict__ pe,
                                                    u16* __restrict__ xs){
  int idx = blockIdx.x * 256 + threadIdx.x;
  if (idx >= NT_ * D_) return;
  int d  = idx % D_;
  int nt = idx / D_;
  int t  = nt % T_;
  int n  = nt / T_;
  float val = x[(((size_t)(n*C_ + (d & 15)))*T_ + t)*V_ + (d >> 4)] + pe[t*D_ + d];
  xs[(size_t)nt * SD_ + d] = f2bf(val);
}

// ---- MFMA GEMM, barrier-free: each wave stages its own 64x64 A/B tiles into a
//      private 16KB LDS quadrant (dbuf), per-wave vmcnt/lgkm waits only.
//      Epilogue: acc -> LDS -> coalesced dwordx4 stores, UNGUARDED into padded
//      buffers (bias=0 for n>=Nn keeps pad cols exactly 0).
template<int ACT>
__global__ __launch_bounds__(256) void gemm_mfma(const u16* __restrict__ A, int lda,
                                                 const u16* __restrict__ B, int ldb,
                                                 const float* __restrict__ bias,
                                                 u16* __restrict__ C, int ldc,
                                                 int Nn, int KPd,
                                                 int gx, int gy){
  __shared__ u16 smem[32768];              // 64KB: 8192 u16 per wave
  int id = blockIdx.x;
  int c  = id & 7, t = id >> 3;
  int bx = t % gx;
  int by = (t / gx) * 8 + c;               // XCD c owns M-tile residue class
  if (by >= gy) return;
  const int m0 = by * 128, n0 = bx * 128;

  const int tid  = threadIdx.x;
  const int lane = tid & 63;
  const int wv   = tid >> 6;
  const int quad = lane >> 4, l16 = lane & 15;
  const int wm   = wv & 1,   wn  = wv >> 1;

  u16* wbase = &smem[wv * 8192];           // [A0|A1|B0|B1] x 2048 u16 each

  const int r16  = lane >> 2;              // row within 16-row group
  const int sseg = (lane & 3) ^ ((lane >> 3) & 3);   // xor-swizzled k-segment
  const u16* Ag = A + (size_t)(m0 + wm*64 + r16) * lda + sseg*8;
  const u16* Bg = B + (size_t)(n0 + wn*64 + r16) * ldb + sseg*8;

  f32x4 acc[4][4] = {};
  const int sa = quad ^ ((l16 >> 1) & 3);  // read-side swizzled slot

  auto stage = [&](int buf, int kt){
    u16* Ad = wbase + buf*2048;
    u16* Bd = wbase + 4096 + buf*2048;
    #pragma unroll
    for (int h = 0; h < 4; ++h){
      __builtin_amdgcn_global_load_lds(
          (const __attribute__((address_space(1))) void*)(Ag + kt + (size_t)(16*h)*lda),
          (__attribute__((address_space(3))) void*)(Ad + h*16*32), 16, 0, 0);
      __builtin_amdgcn_global_load_lds(
          (const __attribute__((address_space(1))) void*)(Bg + kt + (size_t)(16*h)*ldb),
          (__attribute__((address_space(3))) void*)(Bd + h*16*32), 16, 0, 0);
    }
  };

  const int nit = KPd >> 5;
  stage(0, 0);
  if (nit > 1) stage(1, 32);
  for (int it = 0; it < nit; ++it){
    // wait own stage `it` landed (8 loads per stage, <=2 stages in flight)
    if (it < nit - 1) __builtin_amdgcn_s_waitcnt(WAIT_VM8);
    else              __builtin_amdgcn_s_waitcnt(WAIT_VM0);
    const int buf = it & 1;
    const u16* Ar = wbase + buf*2048;
    const u16* Br = wbase + 4096 + buf*2048;
    frag af[4], bfr[4];
    #pragma unroll
    for (int i = 0; i < 4; ++i){
      af[i]  = *(const frag*)(&Ar[(i*16 + l16)*32 + sa*8]);
      bfr[i] = *(const frag*)(&Br[(i*16 + l16)*32 + sa*8]);
    }
    // overlap: first row of MFMAs while remaining ds_reads drain
    #pragma unroll
    for (int j = 0; j < 4; ++j)
      acc[0][j] = __builtin_amdgcn_mfma_f32_16x16x32_bf16(af[0], bfr[j], acc[0][j], 0, 0, 0);
    // frags in registers -> safe to overwrite this buffer with stage it+2
    __builtin_amdgcn_s_waitcnt(WAIT_LGKM0);
    if (it + 2 < nit) stage(buf, (it + 2) << 5);
    #pragma unroll
    for (int i = 1; i < 4; ++i)
      #pragma unroll
      for (int j = 0; j < 4; ++j)
        acc[i][j] = __builtin_amdgcn_mfma_f32_16x16x32_bf16(af[i], bfr[j], acc[i][j], 0, 0, 0);
  }

  // epilogue via wave-private LDS (stride 64 u16), coalesced dwordx4 stores
  u16* tile = wbase;                       // reuse staging region (8192 u16 >= 4096)
  #pragma unroll
  for (int j = 0; j < 4; ++j){
    int n = n0 + wn*64 + j*16 + l16;
    float bj = (n < Nn) ? bias[n] : 0.f;
    #pragma unroll
    for (int i = 0; i < 4; ++i){
      #pragma unroll
      for (int r = 0; r < 4; ++r){
        float v = acc[i][j][r] + bj;
        if (ACT) v = 0.5f * v * (1.f + erff(v * 0.70710678f));
        tile[(i*16 + quad*4 + r)*64 + j*16 + l16] = f2bf(v);
      }
    }
  }
  // per-wave DS ops are in-order; lgkm auto-waited before dependent reads
  #pragma unroll
  for (int p = 0; p < 8; ++p){
    int row = p*8 + (lane >> 3);
    int seg = lane & 7;
    uint4 v = *(const uint4*)(&tile[row*64 + seg*8]);
    *(uint4*)(C + (size_t)(m0 + wm*64 + row)*ldc + n0 + wn*64 + seg*8) = v;
  }
}

// ---- attention for one chunk of windows; 16B vectorized staging ----
__global__ __launch_bounds__(256) void attn_kernel(const u16* __restrict__ qkv,
                                                   u16* __restrict__ o,
                                                   int g0){
  __shared__ float sq[L_ * 1200];
  __shared__ float sc[H_ * L_ * L_];
  __shared__ float att[H_ * L_ * L_];
  const int g = g0 + blockIdx.x;
  const int n = g / W_, w = g % W_;
  const int tid = threadIdx.x;

  for (int i = tid; i < L_ * 150; i += 256){   // 150 16B-chunks per row
    int l = i / 150, ck = i % 150;
    uint4 v = *(const uint4*)(qkv + ((size_t)(n*T_ + w + l)) * SQKV_ + ck*8);
    float* dst = &sq[l*1200 + ck*8];
    dst[0] = bf2f((u16)(v.x & 0xffffu)); dst[1] = bf2f((u16)(v.x >> 16));
    dst[2] = bf2f((u16)(v.y & 0xffffu)); dst[3] = bf2f((u16)(v.y >> 16));
    dst[4] = bf2f((u16)(v.z & 0xffffu)); dst[5] = bf2f((u16)(v.z >> 16));
    dst[6] = bf2f((u16)(v.w & 0xffffu)); dst[7] = bf2f((u16)(v.w >> 16));
  }
  __syncthreads();

  if (tid < H_ * L_ * L_){
    int h = tid / (L_*L_), rem = tid % (L_*L_), qi = rem / L_, ki = rem % L_;
    const float* qp = &sq[qi*1200 + h*DH_];
    const float* kp = &sq[ki*1200 + D_ + h*DH_];
    float s = 0.f;
    for (int dd = 0; dd < DH_; ++dd) s += qp[dd] * kp[dd];
    sc[tid] = s * 0.07071067811865475f;  // 1/sqrt(200)
  }
  __syncthreads();

  if (tid < H_ * L_){
    int base = tid * L_;
    float mx = -1e30f;
    for (int j = 0; j < L_; ++j) mx = fmaxf(mx, sc[base + j]);
    float sum = 0.f;
    for (int j = 0; j < L_; ++j){ float e = __expf(sc[base + j] - mx); att[base + j] = e; sum += e; }
    float inv = 1.f / sum;
    for (int j = 0; j < L_; ++j) att[base + j] *= inv;
  }
  __syncthreads();

  for (int i = tid; i < L_ * D_; i += 256){
    int l = i / D_, d = i % D_;
    int h = d / DH_;
    float a = 0.f;
    #pragma unroll
    for (int ki = 0; ki < L_; ++ki)
      a += att[h*(L_*L_) + l*L_ + ki] * sq[ki*1200 + 2*D_ + d];
    o[((size_t)blockIdx.x * L_ + l) * SD_ + d] = f2bf(a);
  }
}

// ---- LN(a_row + b_row); gather=1: a from xs window. rows stride SD_ ----
__global__ __launch_bounds__(256) void resln_kernel(const u16* a,
                                                    const u16* b,
                                                    const float* __restrict__ gam,
                                                    const float* __restrict__ bet,
                                                    u16* out,
                                                    const u16* __restrict__ xs,
                                                    int g0, int gather){
  const int r = blockIdx.x;
  const int tid = threadIdx.x;
  const u16* arow;
  if (gather){
    int g = g0 + r / L_;
    int l = r % L_;
    int n = g / W_, w = g % W_;
    arow = xs + ((size_t)(n*T_ + w + l)) * SD_;
  } else {
    arow = a + (size_t)r * SD_;
  }
  const u16* brow = b + (size_t)r * SD_;

  float v0 = bf2f(arow[tid]) + bf2f(brow[tid]);
  const bool has1 = (tid + 256) < D_;
  float v1 = has1 ? (bf2f(arow[tid + 256]) + bf2f(brow[tid + 256])) : 0.f;

  __shared__ float red[256];
  red[tid] = v0 + v1;
  __syncthreads();
  for (int s = 128; s > 0; s >>= 1){
    if (tid < s) red[tid] += red[tid + s];
    __syncthreads();
  }
  float mean = red[0] * (1.f / D_);
  __syncthreads();
  float d0 = v0 - mean;
  float d1 = has1 ? (v1 - mean) : 0.f;
  red[tid] = d0*d0 + d1*d1;
  __syncthreads();
  for (int s = 128; s > 0; s >>= 1){
    if (tid < s) red[tid] += red[tid + s];
    __syncthreads();
  }
  float rstd = rsqrtf(red[0] * (1.f / D_) + 1e-5f);
  out[(size_t)r * SD_ + tid] = f2bf(d0 * rstd * gam[tid] + bet[tid]);
  if (has1)
    out[(size_t)r * SD_ + tid + 256] = f2bf(d1 * rstd * gam[tid + 256] + bet[tid + 256]);
}

// ---- scatter-add chunk rows (stride SD_) into fp32 accumulator [N,T,D] ----
__global__ __launch_bounds__(256) void scatter_add_kernel(const u16* __restrict__ win,
                                                          float* __restrict__ acc,
                                                          int g0, int nrows){
  int idx = blockIdx.x * 256 + threadIdx.x;
  if (idx >= nrows * D_) return;
  int d = idx % D_;
  int r = idx / D_;
  int g = g0 + r / L_;
  int l = r % L_;
  int n = g / W_, w = g % W_;
  int t = (w >> 1) + l;
  atomicAdd(acc + ((size_t)(n*T_ + t)) * D_ + d, bf2f(win[(size_t)r * SD_ + d]));
}

// ---- acc[n,t,d] -> out[n,c,t,v] fp32 ----
__global__ __launch_bounds__(256) void final_kernel(const float* __restrict__ acc,
                                                    float* __restrict__ dout){
  int idx = blockIdx.x * 256 + threadIdx.x;
  if (idx >= NT_ * D_) return;
  int d  = idx % D_;
  int nt = idx / D_;
  int t  = nt % T_;
  int n  = nt / T_;
  dout[(((size_t)(n*C_ + (d & 15)))*T_ + t)*V_ + (d >> 4)] = acc[idx];
}

extern "C" void kernel_launch(void* const* d_in, const int* in_sizes, int n_in,
                              void* d_out, int out_size, void* d_ws, size_t ws_size,
                              hipStream_t stream){
  (void)in_sizes; (void)n_in; (void)out_size; (void)ws_size;
  const float* x     = (const float*)d_in[0];
  const float* pe    = (const float*)d_in[1];
  const float* w_in  = (const float*)d_in[2];
  const float* b_in  = (const float*)d_in[3];
  const float* w_out = (const float*)d_in[4];
  const float* b_out = (const float*)d_in[5];
  const float* w1    = (const float*)d_in[6];
  const float* b1    = (const float*)d_in[7];
  const float* w2    = (const float*)d_in[8];
  const float* b2    = (const float*)d_in[9];
  const float* ln1g  = (const float*)d_in[10];
  const float* ln1b  = (const float*)d_in[11];
  const float* ln2g  = (const float*)d_in[12];
  const float* ln2b  = (const float*)d_in[13];

  char* ws = (char*)d_ws;
  u16*   w_in_b  = (u16*)(ws + WIN_OFF);
  u16*   w_out_b = (u16*)(ws + WOUT_OFF);
  u16*   w1_b    = (u16*)(ws + W1_OFF);
  u16*   w2_b    = (u16*)(ws + W2_OFF);
  u16*   xs      = (u16*)(ws + XS_OFF);
  u16*   qkv     = (u16*)(ws + QKV_OFF);
  float* acc     = (float*)(ws + ACC_OFF);
  u16*   o_c     = (u16*)(ws + OC_OFF);
  u16*   y_c     = (u16*)(ws + YC_OFF);
  u16*   h_c     = (u16*)(ws + HC_OFF);
  u16*   ffc     = (u16*)(ws + FFC_OFF);

  convw_kernel<<<(1280*KP_  + 255)/256, 256, 0, stream>>>(w_in,  w_in_b,  1280, KP_, 1200, D_);
  convw_kernel<<<( 512*KP_  + 255)/256, 256, 0, stream>>>(w_out, w_out_b,  512, KP_,  400, D_);
  convw_kernel<<<(1664*KP_  + 255)/256, 256, 0, stream>>>(w1,    w1_b,    1664, KP_, 1600, D_);
  convw_kernel<<<( 512*SFF_ + 255)/256, 256, 0, stream>>>(w2,    w2_b,     512, SFF_, 400, FF_);

  zero_kernel<<<(NT_*D_ + 255)/256, 256, 0, stream>>>(acc, NT_*D_);
  embed_kernel<<<(NT_*D_ + 255)/256, 256, 0, stream>>>(x, pe, xs);

  // qkv = xs @ w_in^T + b_in   [4800 x 1200]
  {
    int gx = SQKV_/128, gy = (NT_ + 127)/128, gy8 = (gy + 7) & ~7;
    gemm_mfma<0><<<gx*gy8, 256, 0, stream>>>(
        xs, SD_, w_in_b, KP_, b_in, qkv, SQKV_, 1200, KP_, gx, gy);
  }

  const int gyc = RCP_/128, gyc8 = (gyc + 7) & ~7;   // 110, 112

  for (int g0 = 0; g0 < NW_; g0 += CW_){
    attn_kernel<<<CW_, 256, 0, stream>>>(qkv, o_c, g0);

    gemm_mfma<0><<<(SD_/128)*gyc8, 256, 0, stream>>>(
        o_c, SD_, w_out_b, KP_, b_out, y_c, SD_, D_, KP_, SD_/128, gyc);

    resln_kernel<<<RC_, 256, 0, stream>>>(nullptr, y_c, ln1g, ln1b, h_c, xs, g0, 1);

    gemm_mfma<1><<<(SFF_/128)*gyc8, 256, 0, stream>>>(
        h_c, SD_, w1_b, KP_, b1, ffc, SFF_, FF_, KP_, SFF_/128, gyc);

    gemm_mfma<0><<<(SD_/128)*gyc8, 256, 0, stream>>>(
        ffc, SFF_, w2_b, SFF_, b2, y_c, SD_, D_, FF_, SD_/128, gyc);

    resln_kernel<<<RC_, 256, 0, stream>>>(h_c, y_c, ln2g, ln2b, h_c, nullptr, g0, 0);

    scatter_add_kernel<<<(RC_*D_ + 255)/256, 256, 0, stream>>>(h_c, acc, g0, RC_);
  }

  final_kernel<<<(NT_*D_ + 255)/256, 256, 0, stream>>>(acc, (float*)d_out);
}

// Round 11
// 602.245 us; speedup vs baseline: 6.8185x; 1.1099x over previous
//
#include <hip/hip_runtime.h>
#include <cstdint>
#include <cstddef>

// ---- problem constants ----
#define N_    16
#define C_    16
#define T_    300
#define V_    25
#define D_    400
#define H_    2
#define DH_   200
#define FF_   1600
#define L_    9
#define W_    291
#define NW_   (N_*W_)      // 4656
#define NT_   (N_*T_)      // 4800
#define CW_   1552         // windows per chunk -> 3 chunks
#define RC_   (CW_*L_)     // 13968 rows per chunk
#define RCP_  14080        // padded chunk rows (110*128)

#define KP_   416          // K-pad of D (mult of 32), zero-filled in weights
#define SD_   512          // row stride of D-wide intermediates
#define SQKV_ 1280         // qkv row stride / QKV N-pad
#define SFF_  1664         // ffc row stride / FFN1 N-pad

// ---- workspace layout (bytes), total 119,803,904 ----
#define WIN_OFF   0u
#define WOUT_OFF  1064960u
#define W1_OFF    1490944u
#define W2_OFF    2875392u
#define XS_OFF    4579328u
#define QKV_OFF   9560064u
#define ACC_OFF   22011904u
#define OC_OFF    29691904u
#define YC_OFF    44109824u
#define HC_OFF    58527744u
#define FFC_OFF   72945664u

// s_waitcnt immediates (gfx9): vmcnt[3:0] | expcnt<<4 | lgkmcnt<<8 | vmcnt[5:4]<<14
#define WAIT_VM4   0xF74    // vmcnt<=4 (oldest stage drained), lgkm/exp don't-care
#define WAIT_VM0   0xF70    // vmcnt<=0

using u16 = unsigned short;
using u32 = unsigned int;
using frag  = __attribute__((ext_vector_type(8))) short;   // 8 bf16
using f32x4 = __attribute__((ext_vector_type(4))) float;

__device__ __forceinline__ float bf2f(u16 u){
  return __uint_as_float(((u32)u) << 16);
}
__device__ __forceinline__ u16 f2bf(float f){
  u32 i = __float_as_uint(f);
  u32 r = (i + 0x7fffu + ((i >> 16) & 1u)) >> 16;   // RNE
  return (u16)r;
}

// exact-gelu via A&S 7.1.26 erf (|err| <= 1.5e-7, invisible under bf16 rounding)
__device__ __forceinline__ float gelu_f(float v){
  float ax = fabsf(v) * 0.70710678118f;
  float t  = 1.f / (1.f + 0.3275911f * ax);
  float y  = t*(0.254829592f + t*(-0.284496736f + t*(1.421413741f +
             t*(-1.453152027f + t*1.061405429f))));
  float er = 1.f - y * __expf(-ax*ax);
  er = (v < 0.f) ? -er : er;
  return 0.5f * v * (1.f + er);
}

__global__ __launch_bounds__(256) void zero_kernel(float* __restrict__ acc, int n){
  int idx = blockIdx.x * 256 + threadIdx.x;
  if (idx < n) acc[idx] = 0.f;
}

// fp32 [sN,sK] -> bf16 [dN,dK], zero-filled pad
__global__ __launch_bounds__(256) void convw_kernel(const float* __restrict__ src,
                                                    u16* __restrict__ dst,
                                                    int dN, int dK, int sN, int sK){
  int idx = blockIdx.x * 256 + threadIdx.x;
  if (idx >= dN * dK) return;
  int n = idx / dK, k = idx % dK;
  dst[idx] = (n < sN && k < sK) ? f2bf(src[(size_t)n * sK + k]) : (u16)0;
}

// ---- xs[nt, d] (stride SD_) = x[n, d&15, t, d>>4] + pe[t,d] ----
__global__ __launch_bounds__(256) void embed_kernel(const float* __restrict__ x,
                                                    const float* __restrict__ pe,
                                                    u16* __restrict__ xs){
  int idx = blockIdx.x * 256 + threadIdx.x;
  if (idx >= NT_ * D_) return;
  int d  = idx % D_;
  int nt = idx / D_;
  int t  = nt % T_;
  int n  = nt / T_;
  float val = x[(((size_t)(n*C_ + (d & 15)))*T_ + t)*V_ + (d >> 4)] + pe[t*D_ + d];
  xs[(size_t)nt * SD_ + d] = f2bf(val);
}

// ---- MFMA GEMM: shared 128x128 tile, 3-deep LDS pipeline, cooperative
//      global_load_lds staging (4 instr/wave/stage), raw s_barrier with
//      s_waitcnt vmcnt(4) (never 0) so 2 stages stay in flight across the
//      barrier. Epilogue via stride-72 LDS tiles -> coalesced dwordx4 stores,
//      UNGUARDED into padded buffers (bias=0 for pad cols keeps pads 0).
template<int ACT>
__global__ __launch_bounds__(256) void gemm_mfma(const u16* __restrict__ A, int lda,
                                                 const u16* __restrict__ B, int ldb,
                                                 const float* __restrict__ bias,
                                                 u16* __restrict__ C, int ldc,
                                                 int Nn, int KPd,
                                                 int gx, int gy){
  __shared__ u16 smem[24576];              // 48KB: A stages [0,12288), B [12288,24576)
  int id = blockIdx.x;
  int c  = id & 7, t = id >> 3;
  int bx = t % gx;
  int by = (t / gx) * 8 + c;               // XCD c owns M-tile residue class
  if (by >= gy) return;
  const int m0 = by * 128, n0 = bx * 128;

  const int tid  = threadIdx.x;
  const int lane = tid & 63;
  const int wv   = tid >> 6;
  const int quad = lane >> 4, l16 = lane & 15;
  const int wm   = wv & 1,   wn  = wv >> 1;

  // staging: wave wv covers rows [wv*32, wv*32+32) of A and of B
  const int rl   = lane >> 2;                          // 0..15 row within group
  const int sseg = (lane & 3) ^ ((lane >> 3) & 3);     // xor-swizzled k-segment
  const u16* Ag = A + (size_t)(m0 + wv*32 + rl) * lda + sseg*8;
  const u16* Bg = B + (size_t)(n0 + wv*32 + rl) * ldb + sseg*8;

  f32x4 acc[4][4] = {};
  const int sa = quad ^ ((l16 >> 1) & 3);              // read-side slot

  auto stage = [&](int buf, int kt){
    u16* Ad = &smem[buf*4096 + (wv*32)*32];
    u16* Bd = &smem[12288 + buf*4096 + (wv*32)*32];
    #pragma unroll
    for (int h = 0; h < 2; ++h){
      __builtin_amdgcn_global_load_lds(
          (const __attribute__((address_space(1))) void*)(Ag + kt + (size_t)(16*h)*lda),
          (__attribute__((address_space(3))) void*)(Ad + h*16*32), 16, 0, 0);
      __builtin_amdgcn_global_load_lds(
          (const __attribute__((address_space(1))) void*)(Bg + kt + (size_t)(16*h)*ldb),
          (__attribute__((address_space(3))) void*)(Bd + h*16*32), 16, 0, 0);
    }
  };

  const int nit = KPd >> 5;                // 13 or 50, always >= 3
  stage(0, 0);
  stage(1, 32);
  int nb = 2;                              // next buffer index (mod 3)
  for (int it = 0; it < nit; ++it){
    // own 4 loads of stage `it` drained (<=1 newer stage outstanding = 4)
    if (it < nit - 1) __builtin_amdgcn_s_waitcnt(WAIT_VM4);
    else              __builtin_amdgcn_s_waitcnt(WAIT_VM0);
    __builtin_amdgcn_s_barrier();          // all waves' quarters of stage it visible
    if (it + 2 < nit){                     // prefetch 2 ahead; buffer freed by barrier
      stage(nb, (it + 2) << 5);
      nb = (nb == 2) ? 0 : nb + 1;
    }
    const int buf = it % 3;
    const u16* Ar = &smem[buf*4096];
    const u16* Br = &smem[12288 + buf*4096];
    frag af[4], bfr[4];
    #pragma unroll
    for (int i = 0; i < 4; ++i){
      af[i]  = *(const frag*)(&Ar[(wm*64 + i*16 + l16)*32 + sa*8]);
      bfr[i] = *(const frag*)(&Br[(wn*64 + i*16 + l16)*32 + sa*8]);
    }
    #pragma unroll
    for (int i = 0; i < 4; ++i)
      #pragma unroll
      for (int j = 0; j < 4; ++j)
        acc[i][j] = __builtin_amdgcn_mfma_f32_16x16x32_bf16(af[i], bfr[j], acc[i][j], 0, 0, 0);
  }

  __builtin_amdgcn_s_barrier();            // all reads done -> staging LDS reusable

  // epilogue: wave-private stride-72 tile (write 2-way=free, read even over banks)
  u16* ep = &smem[wv * 4608];              // 64 rows x 72 u16
  #pragma unroll
  for (int j = 0; j < 4; ++j){
    int n = n0 + wn*64 + j*16 + l16;
    float bj = (n < Nn) ? bias[n] : 0.f;
    #pragma unroll
    for (int i = 0; i < 4; ++i){
      #pragma unroll
      for (int r = 0; r < 4; ++r){
        float v = acc[i][j][r] + bj;
        if (ACT) v = gelu_f(v);
        ep[(i*16 + quad*4 + r)*72 + j*16 + l16] = f2bf(v);
      }
    }
  }
  #pragma unroll
  for (int p = 0; p < 8; ++p){
    int row = p*8 + (lane >> 3);
    int seg = lane & 7;
    uint4 v = *(const uint4*)(&ep[row*72 + seg*8]);
    *(uint4*)(C + (size_t)(m0 + wm*64 + row)*ldc + n0 + wn*64 + seg*8) = v;
  }
}

// ---- attention for one chunk of windows; 16B vectorized staging ----
__global__ __launch_bounds__(256) void attn_kernel(const u16* __restrict__ qkv,
                                                   u16* __restrict__ o,
                                                   int g0){
  __shared__ float sq[L_ * 1200];
  __shared__ float sc[H_ * L_ * L_];
  __shared__ float att[H_ * L_ * L_];
  const int g = g0 + blockIdx.x;
  const int n = g / W_, w = g % W_;
  const int tid = threadIdx.x;

  for (int i = tid; i < L_ * 150; i += 256){   // 150 16B-chunks per row
    int l = i / 150, ck = i % 150;
    uint4 v = *(const uint4*)(qkv + ((size_t)(n*T_ + w + l)) * SQKV_ + ck*8);
    float* dst = &sq[l*1200 + ck*8];
    dst[0] = bf2f((u16)(v.x & 0xffffu)); dst[1] = bf2f((u16)(v.x >> 16));
    dst[2] = bf2f((u16)(v.y & 0xffffu)); dst[3] = bf2f((u16)(v.y >> 16));
    dst[4] = bf2f((u16)(v.z & 0xffffu)); dst[5] = bf2f((u16)(v.z >> 16));
    dst[6] = bf2f((u16)(v.w & 0xffffu)); dst[7] = bf2f((u16)(v.w >> 16));
  }
  __syncthreads();

  if (tid < H_ * L_ * L_){
    int h = tid / (L_*L_), rem = tid % (L_*L_), qi = rem / L_, ki = rem % L_;
    const float* qp = &sq[qi*1200 + h*DH_];
    const float* kp = &sq[ki*1200 + D_ + h*DH_];
    float s = 0.f;
    for (int dd = 0; dd < DH_; ++dd) s += qp[dd] * kp[dd];
    sc[tid] = s * 0.07071067811865475f;  // 1/sqrt(200)
  }
  __syncthreads();

  if (tid < H_ * L_){
    int base = tid * L_;
    float mx = -1e30f;
    for (int j = 0; j < L_; ++j) mx = fmaxf(mx, sc[base + j]);
    float sum = 0.f;
    for (int j = 0; j < L_; ++j){ float e = __expf(sc[base + j] - mx); att[base + j] = e; sum += e; }
    float inv = 1.f / sum;
    for (int j = 0; j < L_; ++j) att[base + j] *= inv;
  }
  __syncthreads();

  for (int i = tid; i < L_ * D_; i += 256){
    int l = i / D_, d = i % D_;
    int h = d / DH_;
    float a = 0.f;
    #pragma unroll
    for (int ki = 0; ki < L_; ++ki)
      a += att[h*(L_*L_) + l*L_ + ki] * sq[ki*1200 + 2*D_ + d];
    o[((size_t)blockIdx.x * L_ + l) * SD_ + d] = f2bf(a);
  }
}

// ---- LN(a_row + b_row); gather=1: a from xs window. rows stride SD_ ----
__global__ __launch_bounds__(256) void resln_kernel(const u16* a,
                                                    const u16* b,
                                                    const float* __restrict__ gam,
                                                    const float* __restrict__ bet,
                                                    u16* out,
                                                    const u16* __restrict__ xs,
                                                    int g0, int gather){
  const int r = blockIdx.x;
  const int tid = threadIdx.x;
  const u16* arow;
  if (gather){
    int g = g0 + r / L_;
    int l = r % L_;
    int n = g / W_, w = g % W_;
    arow = xs + ((size_t)(n*T_ + w + l)) * SD_;
  } else {
    arow = a + (size_t)r * SD_;
  }
  const u16* brow = b + (size_t)r * SD_;

  float v0 = bf2f(arow[tid]) + bf2f(brow[tid]);
  const bool has1 = (tid + 256) < D_;
  float v1 = has1 ? (bf2f(arow[tid + 256]) + bf2f(brow[tid + 256])) : 0.f;

  __shared__ float red[256];
  red[tid] = v0 + v1;
  __syncthreads();
  for (int s = 128; s > 0; s >>= 1){
    if (tid < s) red[tid] += red[tid + s];
    __syncthreads();
  }
  float mean = red[0] * (1.f / D_);
  __syncthreads();
  float d0 = v0 - mean;
  float d1 = has1 ? (v1 - mean) : 0.f;
  red[tid] = d0*d0 + d1*d1;
  __syncthreads();
  for (int s = 128; s > 0; s >>= 1){
    if (tid < s) red[tid] += red[tid + s];
    __syncthreads();
  }
  float rstd = rsqrtf(red[0] * (1.f / D_) + 1e-5f);
  out[(size_t)r * SD_ + tid] = f2bf(d0 * rstd * gam[tid] + bet[tid]);
  if (has1)
    out[(size_t)r * SD_ + tid + 256] = f2bf(d1 * rstd * gam[tid + 256] + bet[tid + 256]);
}

// ---- scatter-add chunk rows (stride SD_) into fp32 accumulator [N,T,D] ----
__global__ __launch_bounds__(256) void scatter_add_kernel(const u16* __restrict__ win,
                                                          float* __restrict__ acc,
                                                          int g0, int nrows){
  int idx = blockIdx.x * 256 + threadIdx.x;
  if (idx >= nrows * D_) return;
  int d = idx % D_;
  int r = idx / D_;
  int g = g0 + r / L_;
  int l = r % L_;
  int n = g / W_, w = g % W_;
  int t = (w >> 1) + l;
  atomicAdd(acc + ((size_t)(n*T_ + t)) * D_ + d, bf2f(win[(size_t)r * SD_ + d]));
}

// ---- acc[n,t,d] -> out[n,c,t,v] fp32 ----
__global__ __launch_bounds__(256) void final_kernel(const float* __restrict__ acc,
                                                    float* __restrict__ dout){
  int idx = blockIdx.x * 256 + threadIdx.x;
  if (idx >= NT_ * D_) return;
  int d  = idx % D_;
  int nt = idx / D_;
  int t  = nt % T_;
  int n  = nt / T_;
  dout[(((size_t)(n*C_ + (d & 15)))*T_ + t)*V_ + (d >> 4)] = acc[idx];
}

extern "C" void kernel_launch(void* const* d_in, const int* in_sizes, int n_in,
                              void* d_out, int out_size, void* d_ws, size_t ws_size,
                              hipStream_t stream){
  (void)in_sizes; (void)n_in; (void)out_size; (void)ws_size;
  const float* x     = (const float*)d_in[0];
  const float* pe    = (const float*)d_in[1];
  const float* w_in  = (const float*)d_in[2];
  const float* b_in  = (const float*)d_in[3];
  const float* w_out = (const float*)d_in[4];
  const float* b_out = (const float*)d_in[5];
  const float* w1    = (const float*)d_in[6];
  const float* b1    = (const float*)d_in[7];
  const float* w2    = (const float*)d_in[8];
  const float* b2    = (const float*)d_in[9];
  const float* ln1g  = (const float*)d_in[10];
  const float* ln1b  = (const float*)d_in[11];
  const float* ln2g  = (const float*)d_in[12];
  const float* ln2b  = (const float*)d_in[13];

  char* ws = (char*)d_ws;
  u16*   w_in_b  = (u16*)(ws + WIN_OFF);
  u16*   w_out_b = (u16*)(ws + WOUT_OFF);
  u16*   w1_b    = (u16*)(ws + W1_OFF);
  u16*   w2_b    = (u16*)(ws + W2_OFF);
  u16*   xs      = (u16*)(ws + XS_OFF);
  u16*   qkv     = (u16*)(ws + QKV_OFF);
  float* acc     = (float*)(ws + ACC_OFF);
  u16*   o_c     = (u16*)(ws + OC_OFF);
  u16*   y_c     = (u16*)(ws + YC_OFF);
  u16*   h_c     = (u16*)(ws + HC_OFF);
  u16*   ffc     = (u16*)(ws + FFC_OFF);

  convw_kernel<<<(1280*KP_  + 255)/256, 256, 0, stream>>>(w_in,  w_in_b,  1280, KP_, 1200, D_);
  convw_kernel<<<( 512*KP_  + 255)/256, 256, 0, stream>>>(w_out, w_out_b,  512, KP_,  400, D_);
  convw_kernel<<<(1664*KP_  + 255)/256, 256, 0, stream>>>(w1,    w1_b,    1664, KP_, 1600, D_);
  convw_kernel<<<( 512*SFF_ + 255)/256, 256, 0, stream>>>(w2,    w2_b,     512, SFF_, 400, FF_);

  zero_kernel<<<(NT_*D_ + 255)/256, 256, 0, stream>>>(acc, NT_*D_);
  embed_kernel<<<(NT_*D_ + 255)/256, 256, 0, stream>>>(x, pe, xs);

  // qkv = xs @ w_in^T + b_in   [4800 x 1200]
  {
    int gx = SQKV_/128, gy = (NT_ + 127)/128, gy8 = (gy + 7) & ~7;
    gemm_mfma<0><<<gx*gy8, 256, 0, stream>>>(
        xs, SD_, w_in_b, KP_, b_in, qkv, SQKV_, 1200, KP_, gx, gy);
  }

  const int gyc = RCP_/128, gyc8 = (gyc + 7) & ~7;   // 110, 112

  for (int g0 = 0; g0 < NW_; g0 += CW_){
    attn_kernel<<<CW_, 256, 0, stream>>>(qkv, o_c, g0);

    gemm_mfma<0><<<(SD_/128)*gyc8, 256, 0, stream>>>(
        o_c, SD_, w_out_b, KP_, b_out, y_c, SD_, D_, KP_, SD_/128, gyc);

    resln_kernel<<<RC_, 256, 0, stream>>>(nullptr, y_c, ln1g, ln1b, h_c, xs, g0, 1);

    gemm_mfma<1><<<(SFF_/128)*gyc8, 256, 0, stream>>>(
        h_c, SD_, w1_b, KP_, b1, ffc, SFF_, FF_, KP_, SFF_/128, gyc);

    gemm_mfma<0><<<(SD_/128)*gyc8, 256, 0, stream>>>(
        ffc, SFF_, w2_b, SFF_, b2, y_c, SD_, D_, FF_, SD_/128, gyc);

    resln_kernel<<<RC_, 256, 0, stream>>>(h_c, y_c, ln2g, ln2b, h_c, nullptr, g0, 0);

    scatter_add_kernel<<<(RC_*D_ + 255)/256, 256, 0, stream>>>(h_c, acc, g0, RC_);
  }

  final_kernel<<<(NT_*D_ + 255)/256, 256, 0, stream>>>(acc, (float*)d_out);
}